// Round 6
// baseline (200.711 us; speedup 1.0000x reference)
//
#include <hip/hip_runtime.h>

typedef __bf16 bf16;
typedef __bf16 bf16x4 __attribute__((ext_vector_type(4)));
typedef __bf16 bf16x8 __attribute__((ext_vector_type(8)));
typedef float floatx4 __attribute__((ext_vector_type(4)));

#define EPS 1.1920929e-07f
// q scale = D^-0.5 * log2(e) folded together (D=64 -> 0.125)
#define QSCALE (0.125f * 1.44269504088896f)
// fixed softmax shift: |q_eff . k| <= ||q_eff||*||k|| = (8*QSCALE)*8 = 11.5416
#define SHIFT_C 11.5416f

__device__ __forceinline__ floatx4 mfma16(bf16x8 a, bf16x8 b, floatx4 c) {
  return __builtin_amdgcn_mfma_f32_16x16x32_bf16(a, b, c, 0, 0, 0);
}

// async 16B global->LDS: HW writes ldsbase + lane*16; gptr is per-lane
__device__ __forceinline__ void gload16(const void* g, void* l) {
  __builtin_amdgcn_global_load_lds((const __attribute__((address_space(1))) unsigned int*)g,
                                   (__attribute__((address_space(3))) unsigned int*)l, 16, 0, 0);
}

// ---------------- prep kernels ----------------
__global__ void cast_x_kernel(const float* __restrict__ x, bf16* __restrict__ xb) {
  int i = (blockIdx.x * blockDim.x + threadIdx.x) * 4;
  float4 v = *(const float4*)(x + i);
  bf16x4 o = {(bf16)v.x, (bf16)v.y, (bf16)v.z, (bf16)v.w};
  *(bf16x4*)(xb + i) = o;
}

// Wqkv_t[n][k] (n<1024: Wq col n; n<1280: Wk col n-1024; else Wv col n-1280), bf16
__global__ void pack_wqkv_kernel(const float* __restrict__ Wq, const float* __restrict__ Wk,
                                 const float* __restrict__ Wv, bf16* __restrict__ out) {
  __shared__ float tile[32][33];
  int n0 = blockIdx.x * 32, k0 = blockIdx.y * 32;
  int tx = threadIdx.x & 31, ty = threadIdx.x >> 5;
#pragma unroll
  for (int i = 0; i < 4; i++) {
    int k = k0 + ty + i * 8, n = n0 + tx;
    float v;
    if (n < 1024)      v = Wq[(size_t)k * 1024 + n];
    else if (n < 1280) v = Wk[(size_t)k * 256 + (n - 1024)];
    else               v = Wv[(size_t)k * 256 + (n - 1280)];
    tile[ty + i * 8][tx] = v;
  }
  __syncthreads();
#pragma unroll
  for (int i = 0; i < 4; i++) {
    int n = n0 + ty + i * 8, k = k0 + tx;
    out[(size_t)n * 1024 + k] = (bf16)tile[tx][ty + i * 8];
  }
}

__global__ void trans_wproj_kernel(const float* __restrict__ W, bf16* __restrict__ out) {
  __shared__ float tile[32][33];
  int n0 = blockIdx.x * 32, k0 = blockIdx.y * 32;
  int tx = threadIdx.x & 31, ty = threadIdx.x >> 5;
#pragma unroll
  for (int i = 0; i < 4; i++)
    tile[ty + i * 8][tx] = W[(size_t)(k0 + ty + i * 8) * 1024 + n0 + tx];
  __syncthreads();
#pragma unroll
  for (int i = 0; i < 4; i++)
    out[(size_t)(n0 + ty + i * 8) * 1024 + k0 + tx] = (bf16)tile[tx][ty + i * 8];
}

// gate[b][kv][s] = 2*sigmoid(x[b,s,:128] . Wgate[:,kv])
__global__ void gate_kernel(const float* __restrict__ x, const float* __restrict__ wgate,
                            float* __restrict__ gate) {
  int tid = blockIdx.x * 256 + threadIdx.x;  // 16384 = 4096 tokens * 4 kv
  int t = tid >> 2, kv = tid & 3;
  const float* xr = x + (size_t)t * 1024;
  float g = 0.f;
#pragma unroll 4
  for (int c = 0; c < 128; c++) g += xr[c] * wgate[c * 4 + kv];
  int b = t >> 11, s = t & 2047;
  gate[((size_t)b * 4 + kv) * 2048 + s] = 2.f / (1.f + __expf(-g));
}

// ---------------- fused QKV GEMM (m97 128x128) + RoPE/RMS/gate epilogue --------------
// n-tile(128): 0-7 -> Q heads (2/tile), 8-9 -> K kv-heads, 10-11 -> V kv-heads.
// Writes Qb [b][h][s][64], Kf/Vf in attention fragment layout directly.
__global__ __launch_bounds__(256) void qkv_gemm_kernel(const bf16* __restrict__ A,
                                                       const bf16* __restrict__ Bt,
                                                       const float* __restrict__ ve,
                                                       const float* __restrict__ cosb,
                                                       const float* __restrict__ sinb,
                                                       const float* __restrict__ gate,
                                                       bf16* __restrict__ Qb,
                                                       bf16* __restrict__ Kf,
                                                       bf16* __restrict__ Vf) {
  __shared__ __align__(16) char smem[36864];  // K-loop: As(8K)+Bs(8K); epilogue: Ep [2][128][72] bf16
  bf16* As = (bf16*)smem;
  bf16* Bs = (bf16*)(smem + 8192);
  bf16* Ep = (bf16*)smem;
  const int K = 1024;
  const int tid = threadIdx.x;
  const int tile = blockIdx.x;
  const int m0 = blockIdx.y * 128, n0 = tile * 128;
  const int w = tid >> 6, lane = tid & 63;
  const int q = lane >> 4, r0 = lane & 15;
  const int wm = w & 1, wn = w >> 1;  // wave = 64m x 64n; cols cover one full head
  const int lrow = lane >> 2, lcol = (lane & 3) * 8;
  const int b = m0 >> 11, s0 = m0 & 2047;

  floatx4 acc[4][4];
#pragma unroll
  for (int i = 0; i < 4; i++)
#pragma unroll
    for (int j = 0; j < 4; j++) acc[i][j] = (floatx4){0.f, 0.f, 0.f, 0.f};

  for (int k0 = 0; k0 < K; k0 += 32) {
    __syncthreads();
    gload16(A + (size_t)(m0 + w * 32 + lrow) * K + k0 + lcol, &As[(w * 32) * 32]);
    gload16(A + (size_t)(m0 + w * 32 + 16 + lrow) * K + k0 + lcol, &As[(w * 32 + 16) * 32]);
    gload16(Bt + (size_t)(n0 + w * 32 + lrow) * K + k0 + lcol, &Bs[(w * 32) * 32]);
    gload16(Bt + (size_t)(n0 + w * 32 + 16 + lrow) * K + k0 + lcol, &Bs[(w * 32 + 16) * 32]);
    __syncthreads();
    bf16x8 af[4], bfr[4];
#pragma unroll
    for (int mt = 0; mt < 4; mt++) af[mt] = *(const bf16x8*)&As[(wm * 64 + mt * 16 + r0) * 32 + q * 8];
#pragma unroll
    for (int nt = 0; nt < 4; nt++) bfr[nt] = *(const bf16x8*)&Bs[(wn * 64 + nt * 16 + r0) * 32 + q * 8];
#pragma unroll
    for (int mt = 0; mt < 4; mt++)
#pragma unroll
      for (int nt = 0; nt < 4; nt++)
        acc[mt][nt] = mfma16(af[mt], bfr[nt], acc[mt][nt]);
  }
  __syncthreads();  // As/Bs dead; Ep reuses the space

  // epilogue: lane owns rows wm*64+mt*16+q*4+r (token - m0), cols wn-head, d = nt*16+r0
  if (tile < 8) {
    // ---- Q: rope -> rms -> *QSCALE -> Ep -> coalesced Qb copy ----
#pragma unroll
    for (int mt = 0; mt < 4; mt++) {
      float rvv[4][4];
#pragma unroll
      for (int ntp = 0; ntp < 2; ntp++) {
        int d31 = ntp * 16 + r0;
#pragma unroll
        for (int r = 0; r < 4; r++) {
          int s = s0 + wm * 64 + mt * 16 + q * 4 + r;
          float c = cosb[s * 32 + d31], sn = sinb[s * 32 + d31];
          float v1 = acc[mt][ntp][r], v2 = acc[mt][ntp + 2][r];
          rvv[ntp][r] = v1 * c + v2 * sn;
          rvv[ntp + 2][r] = v2 * c - v1 * sn;
        }
      }
#pragma unroll
      for (int r = 0; r < 4; r++) {
        float ss = 0.f;
#pragma unroll
        for (int nt = 0; nt < 4; nt++) ss += rvv[nt][r] * rvv[nt][r];
        ss += __shfl_xor(ss, 1, 64);
        ss += __shfl_xor(ss, 2, 64);
        ss += __shfl_xor(ss, 4, 64);
        ss += __shfl_xor(ss, 8, 64);
        float sc = rsqrtf(ss * (1.f / 64.f) + EPS) * QSCALE;
        int row = wm * 64 + mt * 16 + q * 4 + r;
#pragma unroll
        for (int nt = 0; nt < 4; nt++)
          Ep[(wn * 128 + row) * 72 + nt * 16 + r0] = (bf16)(rvv[nt][r] * sc);
      }
    }
    __syncthreads();
#pragma unroll
    for (int p = 0; p < 8; p++) {
      int g = p * 256 + tid;
      int plane = g >> 10, rem = g & 1023, row = rem >> 3, chunk = rem & 7;
      uint4 val = *(const uint4*)&Ep[(plane * 128 + row) * 72 + chunk * 8];
      int h = tile * 2 + plane;
      *(uint4*)&Qb[(((size_t)b * 16 + h) * 2048 + s0 + row) * 64 + chunk * 8] = val;
    }
  } else if (tile < 10) {
    // ---- K: rope -> rms -> Ep -> Kf fragment layout ----
    int kv = (tile - 8) * 2 + wn;
#pragma unroll
    for (int mt = 0; mt < 4; mt++) {
      float rvv[4][4];
#pragma unroll
      for (int ntp = 0; ntp < 2; ntp++) {
        int d31 = ntp * 16 + r0;
#pragma unroll
        for (int r = 0; r < 4; r++) {
          int s = s0 + wm * 64 + mt * 16 + q * 4 + r;
          float c = cosb[s * 32 + d31], sn = sinb[s * 32 + d31];
          float v1 = acc[mt][ntp][r], v2 = acc[mt][ntp + 2][r];
          rvv[ntp][r] = v1 * c + v2 * sn;
          rvv[ntp + 2][r] = v2 * c - v1 * sn;
        }
      }
#pragma unroll
      for (int r = 0; r < 4; r++) {
        float ss = 0.f;
#pragma unroll
        for (int nt = 0; nt < 4; nt++) ss += rvv[nt][r] * rvv[nt][r];
        ss += __shfl_xor(ss, 1, 64);
        ss += __shfl_xor(ss, 2, 64);
        ss += __shfl_xor(ss, 4, 64);
        ss += __shfl_xor(ss, 8, 64);
        float sc = rsqrtf(ss * (1.f / 64.f) + EPS);
        int row = wm * 64 + mt * 16 + q * 4 + r;
#pragma unroll
        for (int nt = 0; nt < 4; nt++)
          Ep[(wn * 128 + row) * 72 + nt * 16 + r0] = (bf16)(rvv[nt][r] * sc);
      }
    }
    __syncthreads();
#pragma unroll
    for (int st = 0; st < 2; st++) {
      int tk = (s0 >> 5) + wm * 2 + st;
      size_t tb = ((size_t)(b * 4 + kv) * 64 + tk) * 2048;
#pragma unroll
      for (int u = 0; u < 4; u++) {
        int joff = (u >= 2) ? 16 : 0, doff = (u & 1) * 32;
        bf16x8 f = *(const bf16x8*)&Ep[(wn * 128 + wm * 64 + st * 32 + joff + r0) * 72 + doff + q * 8];
        *(bf16x8*)&Kf[tb + u * 512 + lane * 8] = f;
      }
    }
  } else {
    // ---- V: + gate*ve -> Ep -> Vf fragment layout ----
    int kv = (tile - 10) * 2 + wn;
    const float* gbase = gate + ((size_t)b * 4 + kv) * 2048;
#pragma unroll
    for (int mt = 0; mt < 4; mt++) {
#pragma unroll
      for (int r = 0; r < 4; r++) {
        int row = wm * 64 + mt * 16 + q * 4 + r;
        int t = m0 + row;
        float gg = gbase[s0 + row];
#pragma unroll
        for (int nt = 0; nt < 4; nt++) {
          int d = nt * 16 + r0;
          float vv = acc[mt][nt][r] + gg * ve[(size_t)t * 256 + kv * 64 + d];
          Ep[(wn * 128 + row) * 72 + d] = (bf16)vv;
        }
      }
    }
    __syncthreads();
#pragma unroll
    for (int st = 0; st < 2; st++) {
      int tk = (s0 >> 5) + wm * 2 + st;
      size_t tb = ((size_t)(b * 4 + kv) * 64 + tk) * 2048;
#pragma unroll
      for (int nt = 0; nt < 4; nt++) {
        bf16 tmp[8];
#pragma unroll
        for (int e = 0; e < 8; e++) {
          int jl = wm * 64 + st * 32 + (e >> 2) * 16 + 4 * q + (e & 3);
          tmp[e] = Ep[(wn * 128 + jl) * 72 + nt * 16 + r0];
        }
        *(uint4*)&Vf[tb + nt * 512 + lane * 8] = *(uint4*)tmp;
      }
    }
  }
}

// ---------------- plain GEMM 128x128 m97 structure: C = A * Bt^T ----------------
template <bool OUT_BF16>
__global__ __launch_bounds__(256) void gemm128_kernel(const bf16* __restrict__ A,
                                                      const bf16* __restrict__ Bt,
                                                      void* __restrict__ Cout,
                                                      int M, int N, int K) {
  __shared__ __align__(16) bf16 As[128 * 32];
  __shared__ __align__(16) bf16 Bs[128 * 32];
  const int tid = threadIdx.x;
  const int m0 = blockIdx.y * 128, n0 = blockIdx.x * 128;
  const int w = tid >> 6, lane = tid & 63;
  const int q = lane >> 4, r0 = lane & 15;
  const int wm = w & 1, wn = w >> 1;
  const int lrow = lane >> 2, lcol = (lane & 3) * 8;

  floatx4 acc[4][4];
#pragma unroll
  for (int i = 0; i < 4; i++)
#pragma unroll
    for (int j = 0; j < 4; j++) acc[i][j] = (floatx4){0.f, 0.f, 0.f, 0.f};

  for (int k0 = 0; k0 < K; k0 += 32) {
    __syncthreads();
    gload16(A + (size_t)(m0 + w * 32 + lrow) * K + k0 + lcol, &As[(w * 32) * 32]);
    gload16(A + (size_t)(m0 + w * 32 + 16 + lrow) * K + k0 + lcol, &As[(w * 32 + 16) * 32]);
    gload16(Bt + (size_t)(n0 + w * 32 + lrow) * K + k0 + lcol, &Bs[(w * 32) * 32]);
    gload16(Bt + (size_t)(n0 + w * 32 + 16 + lrow) * K + k0 + lcol, &Bs[(w * 32 + 16) * 32]);
    __syncthreads();
    bf16x8 af[4], bfr[4];
#pragma unroll
    for (int mt = 0; mt < 4; mt++) af[mt] = *(const bf16x8*)&As[(wm * 64 + mt * 16 + r0) * 32 + q * 8];
#pragma unroll
    for (int nt = 0; nt < 4; nt++) bfr[nt] = *(const bf16x8*)&Bs[(wn * 64 + nt * 16 + r0) * 32 + q * 8];
#pragma unroll
    for (int mt = 0; mt < 4; mt++)
#pragma unroll
      for (int nt = 0; nt < 4; nt++)
        acc[mt][nt] = mfma16(af[mt], bfr[nt], acc[mt][nt]);
  }
#pragma unroll
  for (int mt = 0; mt < 4; mt++)
#pragma unroll
    for (int nt = 0; nt < 4; nt++)
#pragma unroll
      for (int r = 0; r < 4; r++) {
        int row = m0 + wm * 64 + mt * 16 + q * 4 + r;
        int col = n0 + wn * 64 + nt * 16 + r0;
        float v = acc[mt][nt][r];
        if (OUT_BF16) ((bf16*)Cout)[(size_t)row * N + col] = (bf16)v;
        else          ((float*)Cout)[(size_t)row * N + col] = v;
      }
}

// ---------------- flash attention: transposed-S, coalesced frags, split-j, prefetch ----------------
__global__ __launch_bounds__(512, 4) void attn_kernel(const bf16* __restrict__ Qb,
                                                      const bf16* __restrict__ Kf,
                                                      const bf16* __restrict__ Vf,
                                                      const int* __restrict__ wlp,
                                                      const int* __restrict__ wrp,
                                                      bf16* __restrict__ Yb) {
  __shared__ float Ol[4 * 64 * 21];  // upper-half partials: [wq][lane][16 O + 4 L], stride 21
  const int wl = wlp[0];
  const int wrc = min(wrp[0], 0);  // j<=i+wr && j<=i  ==>  j <= i+min(wr,0)
  const int blk = blockIdx.x;
  const int qc = 31 - (blk & 31);  // reversed: longest blocks launch first
  const int bh = blk >> 5;
  const int b = bh >> 4, h = bh & 15, kvh = (bh & 15) >> 2;
  const int w = threadIdx.x >> 6, lane = threadIdx.x & 63;
  const int wq = w & 3, jh = w >> 2;
  const int q = lane >> 4, r0 = lane & 15;
  const int q0 = qc * 64 + wq * 16;

  const bf16* qbase = Qb + (((size_t)b * 16 + h) * 2048 + q0 + r0) * 64;
  bf16x8 aq0 = *(const bf16x8*)(qbase + q * 8);
  bf16x8 aq1 = *(const bf16x8*)(qbase + 32 + q * 8);

  floatx4 Oacc[4];
#pragma unroll
  for (int nt = 0; nt < 4; nt++) Oacc[nt] = (floatx4){0.f, 0.f, 0.f, 0.f};
  floatx4 Lacc = (floatx4){0.f, 0.f, 0.f, 0.f};

  const bf16 onev = (bf16)1.0f;
  const bf16x8 ones = {onev, onev, onev, onev, onev, onev, onev, onev};

  const int jlo0 = max(0, q0 - wl) & ~31;
  const int jhi = q0 + 15 + wrc;
  const int n = ((jhi - jlo0) >> 5) + 1;
  const int nlo = (n + 1) >> 1;
  const int jstart = jh ? jlo0 + (nlo << 5) : jlo0;
  const int count = jh ? n - nlo : nlo;

  const bf16* kfb = Kf + ((size_t)(b * 4 + kvh) * 64) * 2048 + lane * 8;
  const bf16* vfb = Vf + ((size_t)(b * 4 + kvh) * 64) * 2048 + lane * 8;

  if (count > 0) {
    int tile0 = jstart >> 5;
    bf16x8 kf[4], vf[4], nk[4], nv[4];
#pragma unroll
    for (int u = 0; u < 4; u++) {
      kf[u] = *(const bf16x8*)(kfb + (size_t)tile0 * 2048 + u * 512);
      vf[u] = *(const bf16x8*)(vfb + (size_t)tile0 * 2048 + u * 512);
    }

    for (int t = 0; t < count; t++) {
      const int j0 = jstart + (t << 5);
      // prefetch next tile (re-load current on last iter)
      const int tn = (t + 1 < count) ? tile0 + t + 1 : tile0 + t;
#pragma unroll
      for (int u = 0; u < 4; u++) {
        nk[u] = *(const bf16x8*)(kfb + (size_t)tn * 2048 + u * 512);
        nv[u] = *(const bf16x8*)(vfb + (size_t)tn * 2048 + u * 512);
      }

      // St = K·Q^T - SHIFT_C  (C-layout: row j-j0 = 4q+r (+16*sub), col i-q0 = r0)
      floatx4 s0 = (floatx4){-SHIFT_C, -SHIFT_C, -SHIFT_C, -SHIFT_C};
      floatx4 s1 = s0;
      s0 = mfma16(kf[0], aq0, s0);
      s0 = mfma16(kf[1], aq1, s0);
      s1 = mfma16(kf[2], aq0, s1);
      s1 = mfma16(kf[3], aq1, s1);

      bf16x8 pa;
      if (j0 >= q0 + 15 - wl && j0 + 31 <= q0 + wrc) {
#pragma unroll
        for (int r = 0; r < 4; r++) {
          pa[r] = (bf16)exp2f(s0[r]);
          pa[4 + r] = (bf16)exp2f(s1[r]);
        }
      } else {
        const int i = q0 + r0;
#pragma unroll
        for (int r = 0; r < 4; r++) {
          int ja = j0 + 4 * q + r, jb = ja + 16;
          bool va = (ja <= i + wrc) && (ja >= i - wl);
          bool vb = (jb <= i + wrc) && (jb >= i - wl);
          pa[r] = va ? (bf16)exp2f(s0[r]) : (bf16)0.f;
          pa[4 + r] = vb ? (bf16)exp2f(s1[r]) : (bf16)0.f;
        }
      }

      Lacc = mfma16(pa, ones, Lacc);
#pragma unroll
      for (int nt = 0; nt < 4; nt++) Oacc[nt] = mfma16(pa, vf[nt], Oacc[nt]);

#pragma unroll
      for (int u = 0; u < 4; u++) { kf[u] = nk[u]; vf[u] = nv[u]; }
    }
  }

  // merge the two j-halves: upper waves deposit partials, lower waves combine + write
  float* mbase = Ol + (wq * 64 + lane) * 21;
  if (jh == 1) {
#pragma unroll
    for (int nt = 0; nt < 4; nt++)
#pragma unroll
      for (int r = 0; r < 4; r++) mbase[nt * 4 + r] = Oacc[nt][r];
#pragma unroll
    for (int r = 0; r < 4; r++) mbase[16 + r] = Lacc[r];
  }
  __syncthreads();
  if (jh == 0) {
    float inv[4];
#pragma unroll
    for (int r = 0; r < 4; r++) inv[r] = 1.f / (Lacc[r] + mbase[16 + r]);
#pragma unroll
    for (int nt = 0; nt < 4; nt++)
#pragma unroll
      for (int r = 0; r < 4; r++) {
        int i = q0 + q * 4 + r;
        float o = (Oacc[nt][r] + mbase[nt * 4 + r]) * inv[r];
        Yb[((size_t)b * 2048 + i) * 1024 + h * 64 + nt * 16 + r0] = (bf16)o;
      }
  }
}

// ---------------- launch ----------------
extern "C" void kernel_launch(void* const* d_in, const int* in_sizes, int n_in,
                              void* d_out, int out_size, void* d_ws, size_t ws_size,
                              hipStream_t stream) {
  const float* x     = (const float*)d_in[0];
  const float* ve    = (const float*)d_in[1];
  const float* cosb  = (const float*)d_in[2];
  const float* sinb  = (const float*)d_in[3];
  const float* Wq    = (const float*)d_in[4];
  const float* Wk    = (const float*)d_in[5];
  const float* Wv    = (const float*)d_in[6];
  const float* Wproj = (const float*)d_in[7];
  const float* Wgate = (const float*)d_in[8];
  const int* wl      = (const int*)d_in[9];
  const int* wr      = (const int*)d_in[10];

  char* ws = (char*)d_ws;
  bf16* Xb      = (bf16*)(ws);                 //  8,388,608 B: x bf16 [4096][1024]
  bf16* Wqkv_t  = (bf16*)(ws + 8388608);       //  3,145,728 B: [1536][1024]
  bf16* Wproj_t = (bf16*)(ws + 11534336);      //  2,097,152 B: [1024][1024]
  bf16* Qb      = (bf16*)(ws + 13631488);      //  8,388,608 B: [2][16][2048][64]
  bf16* Kf      = (bf16*)(ws + 22020096);      //  2,097,152 B: frag K [8][64 tiles][2048]
  bf16* Vf      = (bf16*)(ws + 24117248);      //  2,097,152 B: frag V
  bf16* Yb      = (bf16*)(ws + 26214400);      //  8,388,608 B: [4096][1024]
  float* gateb  = (float*)(ws + 34603008);     //     65,536 B: [2][4][2048]

  cast_x_kernel<<<4096, 256, 0, stream>>>(x, Xb);
  pack_wqkv_kernel<<<dim3(48, 32), 256, 0, stream>>>(Wq, Wk, Wv, Wqkv_t);
  trans_wproj_kernel<<<dim3(32, 32), 256, 0, stream>>>(Wproj, Wproj_t);
  gate_kernel<<<64, 256, 0, stream>>>(x, Wgate, gateb);
  qkv_gemm_kernel<<<dim3(12, 32), 256, 0, stream>>>(Xb, Wqkv_t, ve, cosb, sinb, gateb, Qb, Kf, Vf);
  attn_kernel<<<1024, 512, 0, stream>>>(Qb, Kf, Vf, wl, wr, Yb);
  gemm128_kernel<false><<<dim3(8, 32), 256, 0, stream>>>(Yb, Wproj_t, d_out, 4096, 1024, 1024);
}

// Round 8
// 182.415 us; speedup vs baseline: 1.1003x; 1.1003x over previous
//
#include <hip/hip_runtime.h>

typedef __bf16 bf16;
typedef __bf16 bf16x4 __attribute__((ext_vector_type(4)));
typedef __bf16 bf16x8 __attribute__((ext_vector_type(8)));
typedef float floatx4 __attribute__((ext_vector_type(4)));

#define EPS 1.1920929e-07f
// q scale = D^-0.5 * log2(e) folded together (D=64 -> 0.125)
#define QSCALE (0.125f * 1.44269504088896f)
// fixed softmax shift: |q_eff . k| <= ||q_eff||*||k|| = (8*QSCALE)*8 = 11.5416
#define SHIFT_C 11.5416f

__device__ __forceinline__ floatx4 mfma16(bf16x8 a, bf16x8 b, floatx4 c) {
  return __builtin_amdgcn_mfma_f32_16x16x32_bf16(a, b, c, 0, 0, 0);
}

// async 16B global->LDS: HW writes ldsbase + lane*16; gptr is per-lane
__device__ __forceinline__ void gload16(const void* g, void* l) {
  __builtin_amdgcn_global_load_lds((const __attribute__((address_space(1))) unsigned int*)g,
                                   (__attribute__((address_space(3))) unsigned int*)l, 16, 0, 0);
}

// ---------------- prep kernels ----------------
__global__ void cast_x_kernel(const float* __restrict__ x, bf16* __restrict__ xb) {
  int i = (blockIdx.x * blockDim.x + threadIdx.x) * 4;
  float4 v = *(const float4*)(x + i);
  bf16x4 o = {(bf16)v.x, (bf16)v.y, (bf16)v.z, (bf16)v.w};
  *(bf16x4*)(xb + i) = o;
}

// Wqkv_t[n][k] (n<1024: Wq col n; n<1280: Wk col n-1024; else Wv col n-1280), bf16
__global__ void pack_wqkv_kernel(const float* __restrict__ Wq, const float* __restrict__ Wk,
                                 const float* __restrict__ Wv, bf16* __restrict__ out) {
  __shared__ float tile[32][33];
  int n0 = blockIdx.x * 32, k0 = blockIdx.y * 32;
  int tx = threadIdx.x & 31, ty = threadIdx.x >> 5;
#pragma unroll
  for (int i = 0; i < 4; i++) {
    int k = k0 + ty + i * 8, n = n0 + tx;
    float v;
    if (n < 1024)      v = Wq[(size_t)k * 1024 + n];
    else if (n < 1280) v = Wk[(size_t)k * 256 + (n - 1024)];
    else               v = Wv[(size_t)k * 256 + (n - 1280)];
    tile[ty + i * 8][tx] = v;
  }
  __syncthreads();
#pragma unroll
  for (int i = 0; i < 4; i++) {
    int n = n0 + ty + i * 8, k = k0 + tx;
    out[(size_t)n * 1024 + k] = (bf16)tile[tx][ty + i * 8];
  }
}

__global__ void trans_wproj_kernel(const float* __restrict__ W, bf16* __restrict__ out) {
  __shared__ float tile[32][33];
  int n0 = blockIdx.x * 32, k0 = blockIdx.y * 32;
  int tx = threadIdx.x & 31, ty = threadIdx.x >> 5;
#pragma unroll
  for (int i = 0; i < 4; i++)
    tile[ty + i * 8][tx] = W[(size_t)(k0 + ty + i * 8) * 1024 + n0 + tx];
  __syncthreads();
#pragma unroll
  for (int i = 0; i < 4; i++)
    out[(size_t)(n0 + ty + i * 8) * 1024 + k0 + tx] = (bf16)tile[tx][ty + i * 8];
}

// gate[b][kv][s] = 2*sigmoid(x[b,s,:128] . Wgate[:,kv])
__global__ void gate_kernel(const float* __restrict__ x, const float* __restrict__ wgate,
                            float* __restrict__ gate) {
  int tid = blockIdx.x * 256 + threadIdx.x;  // 16384 = 4096 tokens * 4 kv
  int t = tid >> 2, kv = tid & 3;
  const float* xr = x + (size_t)t * 1024;
  float g = 0.f;
#pragma unroll 4
  for (int c = 0; c < 128; c++) g += xr[c] * wgate[c * 4 + kv];
  int b = t >> 11, s = t & 2047;
  gate[((size_t)b * 4 + kv) * 2048 + s] = 2.f / (1.f + __expf(-g));
}

// ---------------- fused QKV GEMM: 128m x 64n tiles, BK=64, + RoPE/RMS/gate epilogue ----
// blockIdx.x = n-tile (64 cols = one head): 0-15 Q heads, 16-19 K kv, 20-23 V kv.
// 4 waves, each 32m x 64n. LDS: two 32-col sub-tiles per operand (proven bank-safe layout).
__global__ __launch_bounds__(256) void qkv_gemm_kernel(const bf16* __restrict__ A,
                                                       const bf16* __restrict__ Bt,
                                                       const float* __restrict__ ve,
                                                       const float* __restrict__ cosb,
                                                       const float* __restrict__ sinb,
                                                       const float* __restrict__ gate,
                                                       bf16* __restrict__ Qb,
                                                       bf16* __restrict__ Kf,
                                                       bf16* __restrict__ Vf) {
  __shared__ __align__(16) char smem[24576];  // As 16K (2 halves x 128 x 32) + Bs 8K; epilogue Ep 128x72 bf16
  bf16* As = (bf16*)smem;
  bf16* Bs = (bf16*)(smem + 16384);
  bf16* Ep = (bf16*)smem;
  const int K = 1024;
  const int tid = threadIdx.x;
  const int tile = blockIdx.x;
  const int m0 = blockIdx.y * 128, n0 = tile * 64;
  const int w = tid >> 6, lane = tid & 63;
  const int q = lane >> 4, r0 = lane & 15;
  const int lrow = lane >> 2, lcol = (lane & 3) * 8;
  const int b = m0 >> 11, s0 = m0 & 2047;

  floatx4 acc[2][4];
#pragma unroll
  for (int i = 0; i < 2; i++)
#pragma unroll
    for (int j = 0; j < 4; j++) acc[i][j] = (floatx4){0.f, 0.f, 0.f, 0.f};

  for (int k0 = 0; k0 < K; k0 += 64) {
    __syncthreads();
    // A: 16 gloads (half s, row-block rb): wave w issues g = w*4..w*4+3
#pragma unroll
    for (int i = 0; i < 4; i++) {
      int g = w * 4 + i, s = g >> 3, rb = g & 7;
      gload16(A + (size_t)(m0 + rb * 16 + lrow) * K + k0 + s * 32 + lcol, &As[s * 4096 + rb * 512]);
    }
    // B: 8 gloads: wave w issues g = w*2, w*2+1
#pragma unroll
    for (int i = 0; i < 2; i++) {
      int g = w * 2 + i, s = g >> 2, rb = g & 3;
      gload16(Bt + (size_t)(n0 + rb * 16 + lrow) * K + k0 + s * 32 + lcol, &Bs[s * 2048 + rb * 512]);
    }
    __syncthreads();
#pragma unroll
    for (int s = 0; s < 2; s++) {
      bf16x8 af[2], bfr[4];
#pragma unroll
      for (int mt = 0; mt < 2; mt++) af[mt] = *(const bf16x8*)&As[s * 4096 + (w * 32 + mt * 16 + r0) * 32 + q * 8];
#pragma unroll
      for (int nt = 0; nt < 4; nt++) bfr[nt] = *(const bf16x8*)&Bs[s * 2048 + (nt * 16 + r0) * 32 + q * 8];
#pragma unroll
      for (int mt = 0; mt < 2; mt++)
#pragma unroll
        for (int nt = 0; nt < 4; nt++)
          acc[mt][nt] = mfma16(af[mt], bfr[nt], acc[mt][nt]);
    }
  }
  __syncthreads();  // all LDS reads done; Ep reuses the space

  // lane owns rows w*32 + mt*16 + q*4 + r (token - m0), d = nt*16 + r0
  if (tile < 16) {
    // ---- Q: rope -> rms -> *QSCALE -> Ep -> coalesced Qb copy ----
    const int h = tile;
#pragma unroll
    for (int mt = 0; mt < 2; mt++) {
      float rvv[4][4];
#pragma unroll
      for (int ntp = 0; ntp < 2; ntp++) {
        int d31 = ntp * 16 + r0;
#pragma unroll
        for (int r = 0; r < 4; r++) {
          int s = s0 + w * 32 + mt * 16 + q * 4 + r;
          float c = cosb[s * 32 + d31], sn = sinb[s * 32 + d31];
          float v1 = acc[mt][ntp][r], v2 = acc[mt][ntp + 2][r];
          rvv[ntp][r] = v1 * c + v2 * sn;
          rvv[ntp + 2][r] = v2 * c - v1 * sn;
        }
      }
#pragma unroll
      for (int r = 0; r < 4; r++) {
        float ss = 0.f;
#pragma unroll
        for (int nt = 0; nt < 4; nt++) ss += rvv[nt][r] * rvv[nt][r];
        ss += __shfl_xor(ss, 1, 64);
        ss += __shfl_xor(ss, 2, 64);
        ss += __shfl_xor(ss, 4, 64);
        ss += __shfl_xor(ss, 8, 64);
        float sc = rsqrtf(ss * (1.f / 64.f) + EPS) * QSCALE;
        int row = w * 32 + mt * 16 + q * 4 + r;
#pragma unroll
        for (int nt = 0; nt < 4; nt++)
          Ep[row * 72 + nt * 16 + r0] = (bf16)(rvv[nt][r] * sc);
      }
    }
    __syncthreads();
#pragma unroll
    for (int p = 0; p < 4; p++) {
      int g = p * 256 + tid;
      int row = g >> 3, chunk = g & 7;
      *(uint4*)&Qb[(((size_t)b * 16 + h) * 2048 + s0 + row) * 64 + chunk * 8] =
          *(const uint4*)&Ep[row * 72 + chunk * 8];
    }
  } else if (tile < 20) {
    // ---- K: rope -> rms -> Ep -> Kf fragment layout ----
    const int kv = tile - 16;
#pragma unroll
    for (int mt = 0; mt < 2; mt++) {
      float rvv[4][4];
#pragma unroll
      for (int ntp = 0; ntp < 2; ntp++) {
        int d31 = ntp * 16 + r0;
#pragma unroll
        for (int r = 0; r < 4; r++) {
          int s = s0 + w * 32 + mt * 16 + q * 4 + r;
          float c = cosb[s * 32 + d31], sn = sinb[s * 32 + d31];
          float v1 = acc[mt][ntp][r], v2 = acc[mt][ntp + 2][r];
          rvv[ntp][r] = v1 * c + v2 * sn;
          rvv[ntp + 2][r] = v2 * c - v1 * sn;
        }
      }
#pragma unroll
      for (int r = 0; r < 4; r++) {
        float ss = 0.f;
#pragma unroll
        for (int nt = 0; nt < 4; nt++) ss += rvv[nt][r] * rvv[nt][r];
        ss += __shfl_xor(ss, 1, 64);
        ss += __shfl_xor(ss, 2, 64);
        ss += __shfl_xor(ss, 4, 64);
        ss += __shfl_xor(ss, 8, 64);
        float sc = rsqrtf(ss * (1.f / 64.f) + EPS);
        int row = w * 32 + mt * 16 + q * 4 + r;
#pragma unroll
        for (int nt = 0; nt < 4; nt++)
          Ep[row * 72 + nt * 16 + r0] = (bf16)(rvv[nt][r] * sc);
      }
    }
    __syncthreads();
    // each wave extracts frags for its own 32-key sub-tile
    {
      int tk = (s0 >> 5) + w;
      size_t tb = ((size_t)(b * 4 + kv) * 64 + tk) * 2048;
#pragma unroll
      for (int u = 0; u < 4; u++) {
        int joff = (u >= 2) ? 16 : 0, doff = (u & 1) * 32;
        bf16x8 f = *(const bf16x8*)&Ep[(w * 32 + joff + r0) * 72 + doff + q * 8];
        *(bf16x8*)&Kf[tb + u * 512 + lane * 8] = f;
      }
    }
  } else {
    // ---- V: + gate*ve -> Ep -> Vf fragment layout ----
    const int kv = tile - 20;
    const float* gbase = gate + ((size_t)b * 4 + kv) * 2048;
#pragma unroll
    for (int mt = 0; mt < 2; mt++) {
#pragma unroll
      for (int r = 0; r < 4; r++) {
        int row = w * 32 + mt * 16 + q * 4 + r;
        float gg = gbase[s0 + row];
#pragma unroll
        for (int nt = 0; nt < 4; nt++) {
          int d = nt * 16 + r0;
          float vv = acc[mt][nt][r] + gg * ve[(size_t)(m0 + row) * 256 + kv * 64 + d];
          Ep[row * 72 + d] = (bf16)vv;
        }
      }
    }
    __syncthreads();
    {
      int tk = (s0 >> 5) + w;
      size_t tb = ((size_t)(b * 4 + kv) * 64 + tk) * 2048;
#pragma unroll
      for (int nt = 0; nt < 4; nt++) {
        bf16 tmp[8];
#pragma unroll
        for (int e = 0; e < 8; e++) {
          int jl = w * 32 + (e >> 2) * 16 + 4 * q + (e & 3);
          tmp[e] = Ep[jl * 72 + nt * 16 + r0];
        }
        *(uint4*)&Vf[tb + nt * 512 + lane * 8] = *(uint4*)tmp;
      }
    }
  }
}

// ---------------- proj GEMM: 128m x 64n, BK=64, fp32 out ----------------
__global__ __launch_bounds__(256) void proj_gemm_kernel(const bf16* __restrict__ A,
                                                        const bf16* __restrict__ Bt,
                                                        float* __restrict__ Cout) {
  __shared__ __align__(16) bf16 As[2 * 128 * 32];
  __shared__ __align__(16) bf16 Bs[2 * 64 * 32];
  const int K = 1024, N = 1024;
  const int tid = threadIdx.x;
  const int m0 = blockIdx.y * 128, n0 = blockIdx.x * 64;
  const int w = tid >> 6, lane = tid & 63;
  const int q = lane >> 4, r0 = lane & 15;
  const int lrow = lane >> 2, lcol = (lane & 3) * 8;

  floatx4 acc[2][4];
#pragma unroll
  for (int i = 0; i < 2; i++)
#pragma unroll
    for (int j = 0; j < 4; j++) acc[i][j] = (floatx4){0.f, 0.f, 0.f, 0.f};

  for (int k0 = 0; k0 < K; k0 += 64) {
    __syncthreads();
#pragma unroll
    for (int i = 0; i < 4; i++) {
      int g = w * 4 + i, s = g >> 3, rb = g & 7;
      gload16(A + (size_t)(m0 + rb * 16 + lrow) * K + k0 + s * 32 + lcol, &As[s * 4096 + rb * 512]);
    }
#pragma unroll
    for (int i = 0; i < 2; i++) {
      int g = w * 2 + i, s = g >> 2, rb = g & 3;
      gload16(Bt + (size_t)(n0 + rb * 16 + lrow) * K + k0 + s * 32 + lcol, &Bs[s * 2048 + rb * 512]);
    }
    __syncthreads();
#pragma unroll
    for (int s = 0; s < 2; s++) {
      bf16x8 af[2], bfr[4];
#pragma unroll
      for (int mt = 0; mt < 2; mt++) af[mt] = *(const bf16x8*)&As[s * 4096 + (w * 32 + mt * 16 + r0) * 32 + q * 8];
#pragma unroll
      for (int nt = 0; nt < 4; nt++) bfr[nt] = *(const bf16x8*)&Bs[s * 2048 + (nt * 16 + r0) * 32 + q * 8];
#pragma unroll
      for (int mt = 0; mt < 2; mt++)
#pragma unroll
        for (int nt = 0; nt < 4; nt++)
          acc[mt][nt] = mfma16(af[mt], bfr[nt], acc[mt][nt]);
    }
  }
#pragma unroll
  for (int mt = 0; mt < 2; mt++)
#pragma unroll
    for (int nt = 0; nt < 4; nt++)
#pragma unroll
      for (int r = 0; r < 4; r++) {
        int row = m0 + w * 32 + mt * 16 + q * 4 + r;
        int col = n0 + nt * 16 + r0;
        Cout[(size_t)row * N + col] = acc[mt][nt][r];
      }
}

// ---------------- flash attention: transposed-S, CU-balanced swizzle, split-j, prefetch ----------------
__global__ __launch_bounds__(512, 4) void attn_kernel(const bf16* __restrict__ Qb,
                                                      const bf16* __restrict__ Kf,
                                                      const bf16* __restrict__ Vf,
                                                      const int* __restrict__ wlp,
                                                      const int* __restrict__ wrp,
                                                      bf16* __restrict__ Yb) {
  __shared__ float Ol[4 * 64 * 21];  // upper-half partials: [wq][lane][16 O + 4 L], stride 21
  const int wl = wlp[0];
  const int wrc = min(wrp[0], 0);  // j<=i+wr && j<=i  ==>  j <= i+min(wr,0)
  const int blk = blockIdx.x;
  // CU-balance: CU c gets blocks {c, c+256, c+512, c+768} (round-robin heuristic).
  // qc = (lo + 9*hi) & 31 gives those four blocks qc offsets {0,8,16,24} -> balanced work.
  const int lo = blk & 31, hi = blk >> 5;
  const int qc = (lo + hi * 9) & 31;
  const int bh = hi;
  const int b = bh >> 4, h = bh & 15, kvh = (bh & 15) >> 2;
  const int w = threadIdx.x >> 6, lane = threadIdx.x & 63;
  const int wq = w & 3, jh = w >> 2;
  const int q = lane >> 4, r0 = lane & 15;
  const int q0 = qc * 64 + wq * 16;

  const bf16* qbase = Qb + (((size_t)b * 16 + h) * 2048 + q0 + r0) * 64;
  bf16x8 aq0 = *(const bf16x8*)(qbase + q * 8);
  bf16x8 aq1 = *(const bf16x8*)(qbase + 32 + q * 8);

  floatx4 Oacc[4];
#pragma unroll
  for (int nt = 0; nt < 4; nt++) Oacc[nt] = (floatx4){0.f, 0.f, 0.f, 0.f};
  floatx4 Lacc = (floatx4){0.f, 0.f, 0.f, 0.f};

  const bf16 onev = (bf16)1.0f;
  const bf16x8 ones = {onev, onev, onev, onev, onev, onev, onev, onev};

  const int jlo0 = max(0, q0 - wl) & ~31;
  const int jhi = q0 + 15 + wrc;
  const int n = ((jhi - jlo0) >> 5) + 1;
  const int nlo = (n + 1) >> 1;
  const int jstart = jh ? jlo0 + (nlo << 5) : jlo0;
  const int count = jh ? n - nlo : nlo;

  const bf16* kfb = Kf + ((size_t)(b * 4 + kvh) * 64) * 2048 + lane * 8;
  const bf16* vfb = Vf + ((size_t)(b * 4 + kvh) * 64) * 2048 + lane * 8;

  if (count > 0) {
    int tile0 = jstart >> 5;
    bf16x8 kf[4], vf[4], nk[4], nv[4];
#pragma unroll
    for (int u = 0; u < 4; u++) {
      kf[u] = *(const bf16x8*)(kfb + (size_t)tile0 * 2048 + u * 512);
      vf[u] = *(const bf16x8*)(vfb + (size_t)tile0 * 2048 + u * 512);
    }

    for (int t = 0; t < count; t++) {
      const int j0 = jstart + (t << 5);
      // prefetch next tile (re-load current on last iter)
      const int tn = (t + 1 < count) ? tile0 + t + 1 : tile0 + t;
#pragma unroll
      for (int u = 0; u < 4; u++) {
        nk[u] = *(const bf16x8*)(kfb + (size_t)tn * 2048 + u * 512);
        nv[u] = *(const bf16x8*)(vfb + (size_t)tn * 2048 + u * 512);
      }

      // St = K·Q^T - SHIFT_C  (C-layout: row j-j0 = 4q+r (+16*sub), col i-q0 = r0)
      floatx4 s0 = (floatx4){-SHIFT_C, -SHIFT_C, -SHIFT_C, -SHIFT_C};
      floatx4 s1 = s0;
      s0 = mfma16(kf[0], aq0, s0);
      s0 = mfma16(kf[1], aq1, s0);
      s1 = mfma16(kf[2], aq0, s1);
      s1 = mfma16(kf[3], aq1, s1);

      bf16x8 pa;
      if (j0 >= q0 + 15 - wl && j0 + 31 <= q0 + wrc) {
#pragma unroll
        for (int r = 0; r < 4; r++) {
          pa[r] = (bf16)exp2f(s0[r]);
          pa[4 + r] = (bf16)exp2f(s1[r]);
        }
      } else {
        const int i = q0 + r0;
#pragma unroll
        for (int r = 0; r < 4; r++) {
          int ja = j0 + 4 * q + r, jb = ja + 16;
          bool va = (ja <= i + wrc) && (ja >= i - wl);
          bool vb = (jb <= i + wrc) && (jb >= i - wl);
          pa[r] = va ? (bf16)exp2f(s0[r]) : (bf16)0.f;
          pa[4 + r] = vb ? (bf16)exp2f(s1[r]) : (bf16)0.f;
        }
      }

      Lacc = mfma16(pa, ones, Lacc);
#pragma unroll
      for (int nt = 0; nt < 4; nt++) Oacc[nt] = mfma16(pa, vf[nt], Oacc[nt]);

#pragma unroll
      for (int u = 0; u < 4; u++) { kf[u] = nk[u]; vf[u] = nv[u]; }
    }
  }

  // merge the two j-halves: upper waves deposit partials, lower waves combine + write
  float* mbase = Ol + (wq * 64 + lane) * 21;
  if (jh == 1) {
#pragma unroll
    for (int nt = 0; nt < 4; nt++)
#pragma unroll
      for (int r = 0; r < 4; r++) mbase[nt * 4 + r] = Oacc[nt][r];
#pragma unroll
    for (int r = 0; r < 4; r++) mbase[16 + r] = Lacc[r];
  }
  __syncthreads();
  if (jh == 0) {
    float inv[4];
#pragma unroll
    for (int r = 0; r < 4; r++) inv[r] = 1.f / (Lacc[r] + mbase[16 + r]);
#pragma unroll
    for (int nt = 0; nt < 4; nt++)
#pragma unroll
      for (int r = 0; r < 4; r++) {
        int i = q0 + q * 4 + r;
        float o = (Oacc[nt][r] + mbase[nt * 4 + r]) * inv[r];
        Yb[((size_t)b * 2048 + i) * 1024 + h * 64 + nt * 16 + r0] = (bf16)o;
      }
  }
}

// ---------------- launch ----------------
extern "C" void kernel_launch(void* const* d_in, const int* in_sizes, int n_in,
                              void* d_out, int out_size, void* d_ws, size_t ws_size,
                              hipStream_t stream) {
  const float* x     = (const float*)d_in[0];
  const float* ve    = (const float*)d_in[1];
  const float* cosb  = (const float*)d_in[2];
  const float* sinb  = (const float*)d_in[3];
  const float* Wq    = (const float*)d_in[4];
  const float* Wk    = (const float*)d_in[5];
  const float* Wv    = (const float*)d_in[6];
  const float* Wproj = (const float*)d_in[7];
  const float* Wgate = (const float*)d_in[8];
  const int* wl      = (const int*)d_in[9];
  const int* wr      = (const int*)d_in[10];

  char* ws = (char*)d_ws;
  bf16* Xb      = (bf16*)(ws);                 //  8,388,608 B: x bf16 [4096][1024]
  bf16* Wqkv_t  = (bf16*)(ws + 8388608);       //  3,145,728 B: [1536][1024]
  bf16* Wproj_t = (bf16*)(ws + 11534336);      //  2,097,152 B: [1024][1024]
  bf16* Qb      = (bf16*)(ws + 13631488);      //  8,388,608 B: [2][16][2048][64]
  bf16* Kf      = (bf16*)(ws + 22020096);      //  2,097,152 B: frag K [8][64 tiles][2048]
  bf16* Vf      = (bf16*)(ws + 24117248);      //  2,097,152 B: frag V
  bf16* Yb      = (bf16*)(ws + 26214400);      //  8,388,608 B: [4096][1024]
  float* gateb  = (float*)(ws + 34603008);     //     65,536 B: [2][4][2048]

  cast_x_kernel<<<4096, 256, 0, stream>>>(x, Xb);
  pack_wqkv_kernel<<<dim3(48, 32), 256, 0, stream>>>(Wq, Wk, Wv, Wqkv_t);
  trans_wproj_kernel<<<dim3(32, 32), 256, 0, stream>>>(Wproj, Wproj_t);
  gate_kernel<<<64, 256, 0, stream>>>(x, Wgate, gateb);
  qkv_gemm_kernel<<<dim3(24, 32), 256, 0, stream>>>(Xb, Wqkv_t, ve, cosb, sinb, gateb, Qb, Kf, Vf);
  attn_kernel<<<1024, 512, 0, stream>>>(Qb, Kf, Vf, wl, wr, Yb);
  proj_gemm_kernel<<<dim3(16, 32), 256, 0, stream>>>(Yb, Wproj_t, (float*)d_out);
}

// Round 9
// 179.419 us; speedup vs baseline: 1.1187x; 1.0167x over previous
//
#include <hip/hip_runtime.h>

typedef __bf16 bf16;
typedef __bf16 bf16x4 __attribute__((ext_vector_type(4)));
typedef __bf16 bf16x8 __attribute__((ext_vector_type(8)));
typedef float floatx4 __attribute__((ext_vector_type(4)));

#define EPS 1.1920929e-07f
// q scale = D^-0.5 * log2(e) folded together (D=64 -> 0.125)
#define QSCALE (0.125f * 1.44269504088896f)
// fixed softmax shift: |q_eff . k| <= ||q_eff||*||k|| = (8*QSCALE)*8 = 11.5416
#define SHIFT_C 11.5416f

__device__ __forceinline__ floatx4 mfma16(bf16x8 a, bf16x8 b, floatx4 c) {
  return __builtin_amdgcn_mfma_f32_16x16x32_bf16(a, b, c, 0, 0, 0);
}

// async 16B global->LDS: HW writes ldsbase + lane*16; gptr is per-lane
__device__ __forceinline__ void gload16(const void* g, void* l) {
  __builtin_amdgcn_global_load_lds((const __attribute__((address_space(1))) unsigned int*)g,
                                   (__attribute__((address_space(3))) unsigned int*)l, 16, 0, 0);
}

// ---------------- prep kernels ----------------
__global__ void cast_x_kernel(const float* __restrict__ x, bf16* __restrict__ xb) {
  int i = (blockIdx.x * blockDim.x + threadIdx.x) * 4;
  float4 v = *(const float4*)(x + i);
  bf16x4 o = {(bf16)v.x, (bf16)v.y, (bf16)v.z, (bf16)v.w};
  *(bf16x4*)(xb + i) = o;
}

// Wqkv_t[n][k] (n<1024: Wq col n; n<1280: Wk col n-1024; else Wv col n-1280), bf16
__global__ void pack_wqkv_kernel(const float* __restrict__ Wq, const float* __restrict__ Wk,
                                 const float* __restrict__ Wv, bf16* __restrict__ out) {
  __shared__ float tile[32][33];
  int n0 = blockIdx.x * 32, k0 = blockIdx.y * 32;
  int tx = threadIdx.x & 31, ty = threadIdx.x >> 5;
#pragma unroll
  for (int i = 0; i < 4; i++) {
    int k = k0 + ty + i * 8, n = n0 + tx;
    float v;
    if (n < 1024)      v = Wq[(size_t)k * 1024 + n];
    else if (n < 1280) v = Wk[(size_t)k * 256 + (n - 1024)];
    else               v = Wv[(size_t)k * 256 + (n - 1280)];
    tile[ty + i * 8][tx] = v;
  }
  __syncthreads();
#pragma unroll
  for (int i = 0; i < 4; i++) {
    int n = n0 + ty + i * 8, k = k0 + tx;
    out[(size_t)n * 1024 + k] = (bf16)tile[tx][ty + i * 8];
  }
}

__global__ void trans_wproj_kernel(const float* __restrict__ W, bf16* __restrict__ out) {
  __shared__ float tile[32][33];
  int n0 = blockIdx.x * 32, k0 = blockIdx.y * 32;
  int tx = threadIdx.x & 31, ty = threadIdx.x >> 5;
#pragma unroll
  for (int i = 0; i < 4; i++)
    tile[ty + i * 8][tx] = W[(size_t)(k0 + ty + i * 8) * 1024 + n0 + tx];
  __syncthreads();
#pragma unroll
  for (int i = 0; i < 4; i++)
    out[(size_t)(n0 + ty + i * 8) * 1024 + k0 + tx] = (bf16)tile[tx][ty + i * 8];
}

// gate[b][kv][s] = 2*sigmoid(x[b,s,:128] . Wgate[:,kv])
__global__ void gate_kernel(const float* __restrict__ x, const float* __restrict__ wgate,
                            float* __restrict__ gate) {
  int tid = blockIdx.x * 256 + threadIdx.x;  // 16384 = 4096 tokens * 4 kv
  int t = tid >> 2, kv = tid & 3;
  const float* xr = x + (size_t)t * 1024;
  float g = 0.f;
#pragma unroll 4
  for (int c = 0; c < 128; c++) g += xr[c] * wgate[c * 4 + kv];
  int b = t >> 11, s = t & 2047;
  gate[((size_t)b * 4 + kv) * 2048 + s] = 2.f / (1.f + __expf(-g));
}

// ---------------- fused QKV GEMM: 128m x 64n tiles, BK=64, + RoPE/RMS/gate epilogue ----
// blockIdx.x = n-tile (64 cols = one head): 0-15 Q heads, 16-19 K kv, 20-23 V kv.
// 4 waves, each 32m x 64n. LDS: two 32-col sub-tiles per operand (proven bank-safe layout).
__global__ __launch_bounds__(256) void qkv_gemm_kernel(const bf16* __restrict__ A,
                                                       const bf16* __restrict__ Bt,
                                                       const float* __restrict__ ve,
                                                       const float* __restrict__ cosb,
                                                       const float* __restrict__ sinb,
                                                       const float* __restrict__ gate,
                                                       bf16* __restrict__ Qb,
                                                       bf16* __restrict__ Kf,
                                                       bf16* __restrict__ Vf) {
  __shared__ __align__(16) char smem[24576];  // As 16K (2 halves x 128 x 32) + Bs 8K; epilogue Ep 128x72 bf16
  bf16* As = (bf16*)smem;
  bf16* Bs = (bf16*)(smem + 16384);
  bf16* Ep = (bf16*)smem;
  const int K = 1024;
  const int tid = threadIdx.x;
  const int tile = blockIdx.x;
  const int m0 = blockIdx.y * 128, n0 = tile * 64;
  const int w = tid >> 6, lane = tid & 63;
  const int q = lane >> 4, r0 = lane & 15;
  const int lrow = lane >> 2, lcol = (lane & 3) * 8;
  const int b = m0 >> 11, s0 = m0 & 2047;

  floatx4 acc[2][4];
#pragma unroll
  for (int i = 0; i < 2; i++)
#pragma unroll
    for (int j = 0; j < 4; j++) acc[i][j] = (floatx4){0.f, 0.f, 0.f, 0.f};

  for (int k0 = 0; k0 < K; k0 += 64) {
    __syncthreads();
    // A: 16 gloads (half s, row-block rb): wave w issues g = w*4..w*4+3
#pragma unroll
    for (int i = 0; i < 4; i++) {
      int g = w * 4 + i, s = g >> 3, rb = g & 7;
      gload16(A + (size_t)(m0 + rb * 16 + lrow) * K + k0 + s * 32 + lcol, &As[s * 4096 + rb * 512]);
    }
    // B: 8 gloads: wave w issues g = w*2, w*2+1
#pragma unroll
    for (int i = 0; i < 2; i++) {
      int g = w * 2 + i, s = g >> 2, rb = g & 3;
      gload16(Bt + (size_t)(n0 + rb * 16 + lrow) * K + k0 + s * 32 + lcol, &Bs[s * 2048 + rb * 512]);
    }
    __syncthreads();
#pragma unroll
    for (int s = 0; s < 2; s++) {
      bf16x8 af[2], bfr[4];
#pragma unroll
      for (int mt = 0; mt < 2; mt++) af[mt] = *(const bf16x8*)&As[s * 4096 + (w * 32 + mt * 16 + r0) * 32 + q * 8];
#pragma unroll
      for (int nt = 0; nt < 4; nt++) bfr[nt] = *(const bf16x8*)&Bs[s * 2048 + (nt * 16 + r0) * 32 + q * 8];
#pragma unroll
      for (int mt = 0; mt < 2; mt++)
#pragma unroll
        for (int nt = 0; nt < 4; nt++)
          acc[mt][nt] = mfma16(af[mt], bfr[nt], acc[mt][nt]);
    }
  }
  __syncthreads();  // all LDS reads done; Ep reuses the space

  // lane owns rows w*32 + mt*16 + q*4 + r (token - m0), d = nt*16 + r0
  if (tile < 16) {
    // ---- Q: rope -> rms -> *QSCALE -> Ep -> coalesced Qb copy ----
    const int h = tile;
#pragma unroll
    for (int mt = 0; mt < 2; mt++) {
      float rvv[4][4];
#pragma unroll
      for (int ntp = 0; ntp < 2; ntp++) {
        int d31 = ntp * 16 + r0;
#pragma unroll
        for (int r = 0; r < 4; r++) {
          int s = s0 + w * 32 + mt * 16 + q * 4 + r;
          float c = cosb[s * 32 + d31], sn = sinb[s * 32 + d31];
          float v1 = acc[mt][ntp][r], v2 = acc[mt][ntp + 2][r];
          rvv[ntp][r] = v1 * c + v2 * sn;
          rvv[ntp + 2][r] = v2 * c - v1 * sn;
        }
      }
#pragma unroll
      for (int r = 0; r < 4; r++) {
        float ss = 0.f;
#pragma unroll
        for (int nt = 0; nt < 4; nt++) ss += rvv[nt][r] * rvv[nt][r];
        ss += __shfl_xor(ss, 1, 64);
        ss += __shfl_xor(ss, 2, 64);
        ss += __shfl_xor(ss, 4, 64);
        ss += __shfl_xor(ss, 8, 64);
        float sc = rsqrtf(ss * (1.f / 64.f) + EPS) * QSCALE;
        int row = w * 32 + mt * 16 + q * 4 + r;
#pragma unroll
        for (int nt = 0; nt < 4; nt++)
          Ep[row * 72 + nt * 16 + r0] = (bf16)(rvv[nt][r] * sc);
      }
    }
    __syncthreads();
#pragma unroll
    for (int p = 0; p < 4; p++) {
      int g = p * 256 + tid;
      int row = g >> 3, chunk = g & 7;
      *(uint4*)&Qb[(((size_t)b * 16 + h) * 2048 + s0 + row) * 64 + chunk * 8] =
          *(const uint4*)&Ep[row * 72 + chunk * 8];
    }
  } else if (tile < 20) {
    // ---- K: rope -> rms -> Ep -> Kf fragment layout ----
    const int kv = tile - 16;
#pragma unroll
    for (int mt = 0; mt < 2; mt++) {
      float rvv[4][4];
#pragma unroll
      for (int ntp = 0; ntp < 2; ntp++) {
        int d31 = ntp * 16 + r0;
#pragma unroll
        for (int r = 0; r < 4; r++) {
          int s = s0 + w * 32 + mt * 16 + q * 4 + r;
          float c = cosb[s * 32 + d31], sn = sinb[s * 32 + d31];
          float v1 = acc[mt][ntp][r], v2 = acc[mt][ntp + 2][r];
          rvv[ntp][r] = v1 * c + v2 * sn;
          rvv[ntp + 2][r] = v2 * c - v1 * sn;
        }
      }
#pragma unroll
      for (int r = 0; r < 4; r++) {
        float ss = 0.f;
#pragma unroll
        for (int nt = 0; nt < 4; nt++) ss += rvv[nt][r] * rvv[nt][r];
        ss += __shfl_xor(ss, 1, 64);
        ss += __shfl_xor(ss, 2, 64);
        ss += __shfl_xor(ss, 4, 64);
        ss += __shfl_xor(ss, 8, 64);
        float sc = rsqrtf(ss * (1.f / 64.f) + EPS);
        int row = w * 32 + mt * 16 + q * 4 + r;
#pragma unroll
        for (int nt = 0; nt < 4; nt++)
          Ep[row * 72 + nt * 16 + r0] = (bf16)(rvv[nt][r] * sc);
      }
    }
    __syncthreads();
    // each wave extracts frags for its own 32-key sub-tile
    {
      int tk = (s0 >> 5) + w;
      size_t tb = ((size_t)(b * 4 + kv) * 64 + tk) * 2048;
#pragma unroll
      for (int u = 0; u < 4; u++) {
        int joff = (u >= 2) ? 16 : 0, doff = (u & 1) * 32;
        bf16x8 f = *(const bf16x8*)&Ep[(w * 32 + joff + r0) * 72 + doff + q * 8];
        *(bf16x8*)&Kf[tb + u * 512 + lane * 8] = f;
      }
    }
  } else {
    // ---- V: + gate*ve -> Ep -> Vf fragment layout ----
    const int kv = tile - 20;
    const float* gbase = gate + ((size_t)b * 4 + kv) * 2048;
#pragma unroll
    for (int mt = 0; mt < 2; mt++) {
#pragma unroll
      for (int r = 0; r < 4; r++) {
        int row = w * 32 + mt * 16 + q * 4 + r;
        float gg = gbase[s0 + row];
#pragma unroll
        for (int nt = 0; nt < 4; nt++) {
          int d = nt * 16 + r0;
          float vv = acc[mt][nt][r] + gg * ve[(size_t)(m0 + row) * 256 + kv * 64 + d];
          Ep[row * 72 + d] = (bf16)vv;
        }
      }
    }
    __syncthreads();
    {
      int tk = (s0 >> 5) + w;
      size_t tb = ((size_t)(b * 4 + kv) * 64 + tk) * 2048;
#pragma unroll
      for (int nt = 0; nt < 4; nt++) {
        bf16 tmp[8];
#pragma unroll
        for (int e = 0; e < 8; e++) {
          int jl = w * 32 + (e >> 2) * 16 + 4 * q + (e & 3);
          tmp[e] = Ep[jl * 72 + nt * 16 + r0];
        }
        *(uint4*)&Vf[tb + nt * 512 + lane * 8] = *(uint4*)tmp;
      }
    }
  }
}

// ---------------- proj GEMM: 128m x 64n, BK=64, fp32 out ----------------
__global__ __launch_bounds__(256) void proj_gemm_kernel(const bf16* __restrict__ A,
                                                        const bf16* __restrict__ Bt,
                                                        float* __restrict__ Cout) {
  __shared__ __align__(16) bf16 As[2 * 128 * 32];
  __shared__ __align__(16) bf16 Bs[2 * 64 * 32];
  const int K = 1024, N = 1024;
  const int tid = threadIdx.x;
  const int m0 = blockIdx.y * 128, n0 = blockIdx.x * 64;
  const int w = tid >> 6, lane = tid & 63;
  const int q = lane >> 4, r0 = lane & 15;
  const int lrow = lane >> 2, lcol = (lane & 3) * 8;

  floatx4 acc[2][4];
#pragma unroll
  for (int i = 0; i < 2; i++)
#pragma unroll
    for (int j = 0; j < 4; j++) acc[i][j] = (floatx4){0.f, 0.f, 0.f, 0.f};

  for (int k0 = 0; k0 < K; k0 += 64) {
    __syncthreads();
#pragma unroll
    for (int i = 0; i < 4; i++) {
      int g = w * 4 + i, s = g >> 3, rb = g & 7;
      gload16(A + (size_t)(m0 + rb * 16 + lrow) * K + k0 + s * 32 + lcol, &As[s * 4096 + rb * 512]);
    }
#pragma unroll
    for (int i = 0; i < 2; i++) {
      int g = w * 2 + i, s = g >> 2, rb = g & 3;
      gload16(Bt + (size_t)(n0 + rb * 16 + lrow) * K + k0 + s * 32 + lcol, &Bs[s * 2048 + rb * 512]);
    }
    __syncthreads();
#pragma unroll
    for (int s = 0; s < 2; s++) {
      bf16x8 af[2], bfr[4];
#pragma unroll
      for (int mt = 0; mt < 2; mt++) af[mt] = *(const bf16x8*)&As[s * 4096 + (w * 32 + mt * 16 + r0) * 32 + q * 8];
#pragma unroll
      for (int nt = 0; nt < 4; nt++) bfr[nt] = *(const bf16x8*)&Bs[s * 2048 + (nt * 16 + r0) * 32 + q * 8];
#pragma unroll
      for (int mt = 0; mt < 2; mt++)
#pragma unroll
        for (int nt = 0; nt < 4; nt++)
          acc[mt][nt] = mfma16(af[mt], bfr[nt], acc[mt][nt]);
    }
  }
#pragma unroll
  for (int mt = 0; mt < 2; mt++)
#pragma unroll
    for (int nt = 0; nt < 4; nt++)
#pragma unroll
      for (int r = 0; r < 4; r++) {
        int row = m0 + w * 32 + mt * 16 + q * 4 + r;
        int col = n0 + nt * 16 + r0;
        Cout[(size_t)row * N + col] = acc[mt][nt][r];
      }
}

// ---------------- flash attention: 32 queries/wave, work-uniform blocks, no LDS ----------
// Block p handles 32-query chunks {p, 31-p, 32+p, 63-p} of its (b,h): total work is
// constant across blocks (uniform by construction -> dispatch order irrelevant).
// Each wave: chunks A (q0..q0+15) and B (q0+16..q0+31) share K/V tile loads.
__global__ __launch_bounds__(256, 2) void attn_kernel(const bf16* __restrict__ Qb,
                                                      const bf16* __restrict__ Kf,
                                                      const bf16* __restrict__ Vf,
                                                      const int* __restrict__ wlp,
                                                      const int* __restrict__ wrp,
                                                      bf16* __restrict__ Yb) {
  const int wl = wlp[0];
  const int wrc = min(wrp[0], 0);  // j<=i+wr && j<=i  ==>  j <= i+min(wr,0)
  const int blk = blockIdx.x;
  const int p = blk & 15, bh = blk >> 4;
  const int b = bh >> 4, h = bh & 15, kvh = (bh & 15) >> 2;
  const int w = threadIdx.x >> 6, lane = threadIdx.x & 63;
  const int q = lane >> 4, r0 = lane & 15;
  // balanced chunk set: {p, 31-p, 32+p, 63-p}
  const int cm = (w == 0) ? p : (w == 1) ? 31 - p : (w == 2) ? 32 + p : 63 - p;
  const int q0 = cm * 32;
  const int qA = q0, qB = q0 + 16;

  const bf16* qbase = Qb + (((size_t)b * 16 + h) * 2048 + qA + r0) * 64;
  bf16x8 aqA0 = *(const bf16x8*)(qbase + q * 8);
  bf16x8 aqA1 = *(const bf16x8*)(qbase + 32 + q * 8);
  bf16x8 aqB0 = *(const bf16x8*)(qbase + 16 * 64 + q * 8);
  bf16x8 aqB1 = *(const bf16x8*)(qbase + 16 * 64 + 32 + q * 8);

  floatx4 OA[4], OB[4];
#pragma unroll
  for (int nt = 0; nt < 4; nt++) {
    OA[nt] = (floatx4){0.f, 0.f, 0.f, 0.f};
    OB[nt] = (floatx4){0.f, 0.f, 0.f, 0.f};
  }
  floatx4 LA = (floatx4){0.f, 0.f, 0.f, 0.f};
  floatx4 LB = LA;

  const bf16 onev = (bf16)1.0f;
  const bf16x8 ones = {onev, onev, onev, onev, onev, onev, onev, onev};

  const int jlo = max(0, q0 - wl) & ~31;
  const int jhi = q0 + 31 + wrc;
  const int count = ((jhi - jlo) >> 5) + 1;
  const int tile0 = jlo >> 5;

  const bf16* kfb = Kf + ((size_t)(b * 4 + kvh) * 64) * 2048 + lane * 8;
  const bf16* vfb = Vf + ((size_t)(b * 4 + kvh) * 64) * 2048 + lane * 8;

  bf16x8 kf[4], vf[4], nk[4], nv[4];
#pragma unroll
  for (int u = 0; u < 4; u++) {
    kf[u] = *(const bf16x8*)(kfb + (size_t)tile0 * 2048 + u * 512);
    vf[u] = *(const bf16x8*)(vfb + (size_t)tile0 * 2048 + u * 512);
  }

  for (int t = 0; t < count; t++) {
    const int j0 = jlo + (t << 5);
    // prefetch next tile (re-load current on last iter)
    const int tn = (t + 1 < count) ? tile0 + t + 1 : tile0 + t;
#pragma unroll
    for (int u = 0; u < 4; u++) {
      nk[u] = *(const bf16x8*)(kfb + (size_t)tn * 2048 + u * 512);
      nv[u] = *(const bf16x8*)(vfb + (size_t)tn * 2048 + u * 512);
    }

    // St = K·Q^T - SHIFT_C for both chunks (C-layout: row j-j0 = 4q+r (+16*sub), col = r0)
    floatx4 sA0 = (floatx4){-SHIFT_C, -SHIFT_C, -SHIFT_C, -SHIFT_C};
    floatx4 sA1 = sA0, sB0 = sA0, sB1 = sA0;
    sA0 = mfma16(kf[0], aqA0, sA0);
    sA0 = mfma16(kf[1], aqA1, sA0);
    sA1 = mfma16(kf[2], aqA0, sA1);
    sA1 = mfma16(kf[3], aqA1, sA1);
    sB0 = mfma16(kf[0], aqB0, sB0);
    sB0 = mfma16(kf[1], aqB1, sB0);
    sB1 = mfma16(kf[2], aqB0, sB1);
    sB1 = mfma16(kf[3], aqB1, sB1);

    bf16x8 paA, paB;
    // chunk A mask/exp
    if (j0 >= qA + 15 - wl && j0 + 31 <= qA + wrc) {
#pragma unroll
      for (int r = 0; r < 4; r++) {
        paA[r] = (bf16)exp2f(sA0[r]);
        paA[4 + r] = (bf16)exp2f(sA1[r]);
      }
    } else {
      const int i = qA + r0;
#pragma unroll
      for (int r = 0; r < 4; r++) {
        int ja = j0 + 4 * q + r, jb = ja + 16;
        bool va = (ja <= i + wrc) && (ja >= i - wl);
        bool vb = (jb <= i + wrc) && (jb >= i - wl);
        paA[r] = va ? (bf16)exp2f(sA0[r]) : (bf16)0.f;
        paA[4 + r] = vb ? (bf16)exp2f(sA1[r]) : (bf16)0.f;
      }
    }
    // chunk B mask/exp
    if (j0 >= qB + 15 - wl && j0 + 31 <= qB + wrc) {
#pragma unroll
      for (int r = 0; r < 4; r++) {
        paB[r] = (bf16)exp2f(sB0[r]);
        paB[4 + r] = (bf16)exp2f(sB1[r]);
      }
    } else {
      const int i = qB + r0;
#pragma unroll
      for (int r = 0; r < 4; r++) {
        int ja = j0 + 4 * q + r, jb = ja + 16;
        bool va = (ja <= i + wrc) && (ja >= i - wl);
        bool vb = (jb <= i + wrc) && (jb >= i - wl);
        paB[r] = va ? (bf16)exp2f(sB0[r]) : (bf16)0.f;
        paB[4 + r] = vb ? (bf16)exp2f(sB1[r]) : (bf16)0.f;
      }
    }

    LA = mfma16(paA, ones, LA);
    LB = mfma16(paB, ones, LB);
#pragma unroll
    for (int nt = 0; nt < 4; nt++) {
      OA[nt] = mfma16(paA, vf[nt], OA[nt]);
      OB[nt] = mfma16(paB, vf[nt], OB[nt]);
    }

#pragma unroll
    for (int u = 0; u < 4; u++) { kf[u] = nk[u]; vf[u] = nv[u]; }
  }

  // O/L C-layout: row i-qX = q*4+r, col d = nt*16+r0
  float invA[4], invB[4];
#pragma unroll
  for (int r = 0; r < 4; r++) {
    invA[r] = 1.f / LA[r];
    invB[r] = 1.f / LB[r];
  }
#pragma unroll
  for (int nt = 0; nt < 4; nt++)
#pragma unroll
    for (int r = 0; r < 4; r++) {
      int iA = qA + q * 4 + r;
      Yb[((size_t)b * 2048 + iA) * 1024 + h * 64 + nt * 16 + r0] = (bf16)(OA[nt][r] * invA[r]);
      int iB = qB + q * 4 + r;
      Yb[((size_t)b * 2048 + iB) * 1024 + h * 64 + nt * 16 + r0] = (bf16)(OB[nt][r] * invB[r]);
    }
}

// ---------------- launch ----------------
extern "C" void kernel_launch(void* const* d_in, const int* in_sizes, int n_in,
                              void* d_out, int out_size, void* d_ws, size_t ws_size,
                              hipStream_t stream) {
  const float* x     = (const float*)d_in[0];
  const float* ve    = (const float*)d_in[1];
  const float* cosb  = (const float*)d_in[2];
  const float* sinb  = (const float*)d_in[3];
  const float* Wq    = (const float*)d_in[4];
  const float* Wk    = (const float*)d_in[5];
  const float* Wv    = (const float*)d_in[6];
  const float* Wproj = (const float*)d_in[7];
  const float* Wgate = (const float*)d_in[8];
  const int* wl      = (const int*)d_in[9];
  const int* wr      = (const int*)d_in[10];

  char* ws = (char*)d_ws;
  bf16* Xb      = (bf16*)(ws);                 //  8,388,608 B: x bf16 [4096][1024]
  bf16* Wqkv_t  = (bf16*)(ws + 8388608);       //  3,145,728 B: [1536][1024]
  bf16* Wproj_t = (bf16*)(ws + 11534336);      //  2,097,152 B: [1024][1024]
  bf16* Qb      = (bf16*)(ws + 13631488);      //  8,388,608 B: [2][16][2048][64]
  bf16* Kf      = (bf16*)(ws + 22020096);      //  2,097,152 B: frag K [8][64 tiles][2048]
  bf16* Vf      = (bf16*)(ws + 24117248);      //  2,097,152 B: frag V
  bf16* Yb      = (bf16*)(ws + 26214400);      //  8,388,608 B: [4096][1024]
  float* gateb  = (float*)(ws + 34603008);     //     65,536 B: [2][4][2048]

  cast_x_kernel<<<4096, 256, 0, stream>>>(x, Xb);
  pack_wqkv_kernel<<<dim3(48, 32), 256, 0, stream>>>(Wq, Wk, Wv, Wqkv_t);
  trans_wproj_kernel<<<dim3(32, 32), 256, 0, stream>>>(Wproj, Wproj_t);
  gate_kernel<<<64, 256, 0, stream>>>(x, Wgate, gateb);
  qkv_gemm_kernel<<<dim3(24, 32), 256, 0, stream>>>(Xb, Wqkv_t, ve, cosb, sinb, gateb, Qb, Kf, Vf);
  attn_kernel<<<512, 256, 0, stream>>>(Qb, Kf, Vf, wl, wr, Yb);
  proj_gemm_kernel<<<dim3(16, 32), 256, 0, stream>>>(Yb, Wproj_t, (float*)d_out);
}

// Round 11
// 171.965 us; speedup vs baseline: 1.1672x; 1.0433x over previous
//
#include <hip/hip_runtime.h>

typedef __bf16 bf16;
typedef __bf16 bf16x4 __attribute__((ext_vector_type(4)));
typedef __bf16 bf16x8 __attribute__((ext_vector_type(8)));
typedef float floatx4 __attribute__((ext_vector_type(4)));

#define EPS 1.1920929e-07f
// q scale = D^-0.5 * log2(e) folded together (D=64 -> 0.125)
#define QSCALE (0.125f * 1.44269504088896f)
// fixed softmax shift: |q_eff . k| <= ||q_eff||*||k|| = (8*QSCALE)*8 = 11.5416
#define SHIFT_C 11.5416f

__device__ __forceinline__ floatx4 mfma16(bf16x8 a, bf16x8 b, floatx4 c) {
  return __builtin_amdgcn_mfma_f32_16x16x32_bf16(a, b, c, 0, 0, 0);
}

// async 16B global->LDS: HW writes ldsbase + lane*16; gptr is per-lane
__device__ __forceinline__ void gload16(const void* g, void* l) {
  __builtin_amdgcn_global_load_lds((const __attribute__((address_space(1))) unsigned int*)g,
                                   (__attribute__((address_space(3))) unsigned int*)l, 16, 0, 0);
}

// ---------------- fused cast + gate: one block per token ----------------
// All 64 lanes of wave 0 run the reduction branch-free (lanes 32..63 compute a
// redundant partial over x[128:256] that is never read); write predicated to lane 0.
__global__ void cast_gate_kernel(const float* __restrict__ x, const float* __restrict__ wgate,
                                 bf16* __restrict__ xb, float* __restrict__ gate) {
  int t = blockIdx.x, tid = threadIdx.x;
  const float* xr = x + (size_t)t * 1024;
  float4 v = *(const float4*)(xr + tid * 4);
  bf16x4 o = {(bf16)v.x, (bf16)v.y, (bf16)v.z, (bf16)v.w};
  *(bf16x4*)(xb + (size_t)t * 1024 + tid * 4) = o;
  if (tid < 64) {
    int c = (tid & 31) * 4;  // gate columns come from lanes 0..31 only
#pragma unroll
    for (int kv = 0; kv < 4; kv++) {
      float g = v.x * wgate[(c + 0) * 4 + kv] + v.y * wgate[(c + 1) * 4 + kv] +
                v.z * wgate[(c + 2) * 4 + kv] + v.w * wgate[(c + 3) * 4 + kv];
      g += __shfl_xor(g, 1, 64);
      g += __shfl_xor(g, 2, 64);
      g += __shfl_xor(g, 4, 64);
      g += __shfl_xor(g, 8, 64);
      g += __shfl_xor(g, 16, 64);
      if (tid == 0) {
        int b = t >> 11, s = t & 2047;
        gate[((size_t)b * 4 + kv) * 2048 + s] = 2.f / (1.f + __expf(-g));
      }
    }
  }
}

// ---------------- combined weight pack: qkv (x<48) + wproj (x>=48) ----------------
__global__ void pack_w_kernel(const float* __restrict__ Wq, const float* __restrict__ Wk,
                              const float* __restrict__ Wv, const float* __restrict__ Wproj,
                              bf16* __restrict__ out_qkv, bf16* __restrict__ out_proj) {
  __shared__ float tile[32][33];
  int k0 = blockIdx.y * 32;
  int tx = threadIdx.x & 31, ty = threadIdx.x >> 5;
  if (blockIdx.x < 48) {
    int n0 = blockIdx.x * 32;
#pragma unroll
    for (int i = 0; i < 4; i++) {
      int k = k0 + ty + i * 8, n = n0 + tx;
      float v;
      if (n < 1024)      v = Wq[(size_t)k * 1024 + n];
      else if (n < 1280) v = Wk[(size_t)k * 256 + (n - 1024)];
      else               v = Wv[(size_t)k * 256 + (n - 1280)];
      tile[ty + i * 8][tx] = v;
    }
    __syncthreads();
#pragma unroll
    for (int i = 0; i < 4; i++) {
      int n = n0 + ty + i * 8, k = k0 + tx;
      out_qkv[(size_t)n * 1024 + k] = (bf16)tile[tx][ty + i * 8];
    }
  } else {
    int n0 = (blockIdx.x - 48) * 32;
#pragma unroll
    for (int i = 0; i < 4; i++)
      tile[ty + i * 8][tx] = Wproj[(size_t)(k0 + ty + i * 8) * 1024 + n0 + tx];
    __syncthreads();
#pragma unroll
    for (int i = 0; i < 4; i++)
      out_proj[(size_t)(n0 + ty + i * 8) * 1024 + k0 + tx] = (bf16)tile[tx][ty + i * 8];
  }
}

// ---------------- fused QKV GEMM: 128m x 64n tiles, BK=64, + RoPE/RMS/gate epilogue ----
// blockIdx.x = n-tile (64 cols = one head): 0-15 Q heads, 16-19 K kv, 20-23 V kv.
// 4 waves, each 32m x 64n. LDS: two 32-col sub-tiles per operand (proven bank-safe layout).
__global__ __launch_bounds__(256) void qkv_gemm_kernel(const bf16* __restrict__ A,
                                                       const bf16* __restrict__ Bt,
                                                       const float* __restrict__ ve,
                                                       const float* __restrict__ cosb,
                                                       const float* __restrict__ sinb,
                                                       const float* __restrict__ gate,
                                                       bf16* __restrict__ Qb,
                                                       bf16* __restrict__ Kf,
                                                       bf16* __restrict__ Vf) {
  __shared__ __align__(16) char smem[24576];  // As 16K (2 halves x 128 x 32) + Bs 8K; epilogue Ep 128x72 bf16
  bf16* As = (bf16*)smem;
  bf16* Bs = (bf16*)(smem + 16384);
  bf16* Ep = (bf16*)smem;
  const int K = 1024;
  const int tid = threadIdx.x;
  const int tile = blockIdx.x;
  const int m0 = blockIdx.y * 128, n0 = tile * 64;
  const int w = tid >> 6, lane = tid & 63;
  const int q = lane >> 4, r0 = lane & 15;
  const int lrow = lane >> 2, lcol = (lane & 3) * 8;
  const int b = m0 >> 11, s0 = m0 & 2047;

  floatx4 acc[2][4];
#pragma unroll
  for (int i = 0; i < 2; i++)
#pragma unroll
    for (int j = 0; j < 4; j++) acc[i][j] = (floatx4){0.f, 0.f, 0.f, 0.f};

  for (int k0 = 0; k0 < K; k0 += 64) {
    __syncthreads();
    // A: 16 gloads (half s, row-block rb): wave w issues g = w*4..w*4+3
#pragma unroll
    for (int i = 0; i < 4; i++) {
      int g = w * 4 + i, s = g >> 3, rb = g & 7;
      gload16(A + (size_t)(m0 + rb * 16 + lrow) * K + k0 + s * 32 + lcol, &As[s * 4096 + rb * 512]);
    }
    // B: 8 gloads: wave w issues g = w*2, w*2+1
#pragma unroll
    for (int i = 0; i < 2; i++) {
      int g = w * 2 + i, s = g >> 2, rb = g & 3;
      gload16(Bt + (size_t)(n0 + rb * 16 + lrow) * K + k0 + s * 32 + lcol, &Bs[s * 2048 + rb * 512]);
    }
    __syncthreads();
#pragma unroll
    for (int s = 0; s < 2; s++) {
      bf16x8 af[2], bfr[4];
#pragma unroll
      for (int mt = 0; mt < 2; mt++) af[mt] = *(const bf16x8*)&As[s * 4096 + (w * 32 + mt * 16 + r0) * 32 + q * 8];
#pragma unroll
      for (int nt = 0; nt < 4; nt++) bfr[nt] = *(const bf16x8*)&Bs[s * 2048 + (nt * 16 + r0) * 32 + q * 8];
#pragma unroll
      for (int mt = 0; mt < 2; mt++)
#pragma unroll
        for (int nt = 0; nt < 4; nt++)
          acc[mt][nt] = mfma16(af[mt], bfr[nt], acc[mt][nt]);
    }
  }
  __syncthreads();  // all LDS reads done; Ep reuses the space

  // lane owns rows w*32 + mt*16 + q*4 + r (token - m0), d = nt*16 + r0
  if (tile < 16) {
    // ---- Q: rope -> rms -> *QSCALE -> Ep -> coalesced Qb copy ----
    const int h = tile;
#pragma unroll
    for (int mt = 0; mt < 2; mt++) {
      float rvv[4][4];
#pragma unroll
      for (int ntp = 0; ntp < 2; ntp++) {
        int d31 = ntp * 16 + r0;
#pragma unroll
        for (int r = 0; r < 4; r++) {
          int s = s0 + w * 32 + mt * 16 + q * 4 + r;
          float c = cosb[s * 32 + d31], sn = sinb[s * 32 + d31];
          float v1 = acc[mt][ntp][r], v2 = acc[mt][ntp + 2][r];
          rvv[ntp][r] = v1 * c + v2 * sn;
          rvv[ntp + 2][r] = v2 * c - v1 * sn;
        }
      }
#pragma unroll
      for (int r = 0; r < 4; r++) {
        float ss = 0.f;
#pragma unroll
        for (int nt = 0; nt < 4; nt++) ss += rvv[nt][r] * rvv[nt][r];
        ss += __shfl_xor(ss, 1, 64);
        ss += __shfl_xor(ss, 2, 64);
        ss += __shfl_xor(ss, 4, 64);
        ss += __shfl_xor(ss, 8, 64);
        float sc = rsqrtf(ss * (1.f / 64.f) + EPS) * QSCALE;
        int row = w * 32 + mt * 16 + q * 4 + r;
#pragma unroll
        for (int nt = 0; nt < 4; nt++)
          Ep[row * 72 + nt * 16 + r0] = (bf16)(rvv[nt][r] * sc);
      }
    }
    __syncthreads();
#pragma unroll
    for (int p = 0; p < 4; p++) {
      int g = p * 256 + tid;
      int row = g >> 3, chunk = g & 7;
      *(uint4*)&Qb[(((size_t)b * 16 + h) * 2048 + s0 + row) * 64 + chunk * 8] =
          *(const uint4*)&Ep[row * 72 + chunk * 8];
    }
  } else if (tile < 20) {
    // ---- K: rope -> rms -> Ep -> Kf fragment layout ----
    const int kv = tile - 16;
#pragma unroll
    for (int mt = 0; mt < 2; mt++) {
      float rvv[4][4];
#pragma unroll
      for (int ntp = 0; ntp < 2; ntp++) {
        int d31 = ntp * 16 + r0;
#pragma unroll
        for (int r = 0; r < 4; r++) {
          int s = s0 + w * 32 + mt * 16 + q * 4 + r;
          float c = cosb[s * 32 + d31], sn = sinb[s * 32 + d31];
          float v1 = acc[mt][ntp][r], v2 = acc[mt][ntp + 2][r];
          rvv[ntp][r] = v1 * c + v2 * sn;
          rvv[ntp + 2][r] = v2 * c - v1 * sn;
        }
      }
#pragma unroll
      for (int r = 0; r < 4; r++) {
        float ss = 0.f;
#pragma unroll
        for (int nt = 0; nt < 4; nt++) ss += rvv[nt][r] * rvv[nt][r];
        ss += __shfl_xor(ss, 1, 64);
        ss += __shfl_xor(ss, 2, 64);
        ss += __shfl_xor(ss, 4, 64);
        ss += __shfl_xor(ss, 8, 64);
        float sc = rsqrtf(ss * (1.f / 64.f) + EPS);
        int row = w * 32 + mt * 16 + q * 4 + r;
#pragma unroll
        for (int nt = 0; nt < 4; nt++)
          Ep[row * 72 + nt * 16 + r0] = (bf16)(rvv[nt][r] * sc);
      }
    }
    __syncthreads();
    // each wave extracts frags for its own 32-key sub-tile
    {
      int tk = (s0 >> 5) + w;
      size_t tb = ((size_t)(b * 4 + kv) * 64 + tk) * 2048;
#pragma unroll
      for (int u = 0; u < 4; u++) {
        int joff = (u >= 2) ? 16 : 0, doff = (u & 1) * 32;
        bf16x8 f = *(const bf16x8*)&Ep[(w * 32 + joff + r0) * 72 + doff + q * 8];
        *(bf16x8*)&Kf[tb + u * 512 + lane * 8] = f;
      }
    }
  } else {
    // ---- V: + gate*ve -> Ep -> Vf fragment layout ----
    const int kv = tile - 20;
    const float* gbase = gate + ((size_t)b * 4 + kv) * 2048;
#pragma unroll
    for (int mt = 0; mt < 2; mt++) {
#pragma unroll
      for (int r = 0; r < 4; r++) {
        int row = w * 32 + mt * 16 + q * 4 + r;
        float gg = gbase[s0 + row];
#pragma unroll
        for (int nt = 0; nt < 4; nt++) {
          int d = nt * 16 + r0;
          float vv = acc[mt][nt][r] + gg * ve[(size_t)(m0 + row) * 256 + kv * 64 + d];
          Ep[row * 72 + d] = (bf16)vv;
        }
      }
    }
    __syncthreads();
    {
      int tk = (s0 >> 5) + w;
      size_t tb = ((size_t)(b * 4 + kv) * 64 + tk) * 2048;
#pragma unroll
      for (int nt = 0; nt < 4; nt++) {
        bf16 tmp[8];
#pragma unroll
        for (int e = 0; e < 8; e++) {
          int jl = w * 32 + (e >> 2) * 16 + 4 * q + (e & 3);
          tmp[e] = Ep[jl * 72 + nt * 16 + r0];
        }
        *(uint4*)&Vf[tb + nt * 512 + lane * 8] = *(uint4*)tmp;
      }
    }
  }
}

// ---------------- proj GEMM: 128m x 64n, BK=64, fp32 out ----------------
__global__ __launch_bounds__(256) void proj_gemm_kernel(const bf16* __restrict__ A,
                                                        const bf16* __restrict__ Bt,
                                                        float* __restrict__ Cout) {
  __shared__ __align__(16) bf16 As[2 * 128 * 32];
  __shared__ __align__(16) bf16 Bs[2 * 64 * 32];
  const int K = 1024, N = 1024;
  const int tid = threadIdx.x;
  const int m0 = blockIdx.y * 128, n0 = blockIdx.x * 64;
  const int w = tid >> 6, lane = tid & 63;
  const int q = lane >> 4, r0 = lane & 15;
  const int lrow = lane >> 2, lcol = (lane & 3) * 8;

  floatx4 acc[2][4];
#pragma unroll
  for (int i = 0; i < 2; i++)
#pragma unroll
    for (int j = 0; j < 4; j++) acc[i][j] = (floatx4){0.f, 0.f, 0.f, 0.f};

  for (int k0 = 0; k0 < K; k0 += 64) {
    __syncthreads();
#pragma unroll
    for (int i = 0; i < 4; i++) {
      int g = w * 4 + i, s = g >> 3, rb = g & 7;
      gload16(A + (size_t)(m0 + rb * 16 + lrow) * K + k0 + s * 32 + lcol, &As[s * 4096 + rb * 512]);
    }
#pragma unroll
    for (int i = 0; i < 2; i++) {
      int g = w * 2 + i, s = g >> 2, rb = g & 3;
      gload16(Bt + (size_t)(n0 + rb * 16 + lrow) * K + k0 + s * 32 + lcol, &Bs[s * 2048 + rb * 512]);
    }
    __syncthreads();
#pragma unroll
    for (int s = 0; s < 2; s++) {
      bf16x8 af[2], bfr[4];
#pragma unroll
      for (int mt = 0; mt < 2; mt++) af[mt] = *(const bf16x8*)&As[s * 4096 + (w * 32 + mt * 16 + r0) * 32 + q * 8];
#pragma unroll
      for (int nt = 0; nt < 4; nt++) bfr[nt] = *(const bf16x8*)&Bs[s * 2048 + (nt * 16 + r0) * 32 + q * 8];
#pragma unroll
      for (int mt = 0; mt < 2; mt++)
#pragma unroll
        for (int nt = 0; nt < 4; nt++)
          acc[mt][nt] = mfma16(af[mt], bfr[nt], acc[mt][nt]);
    }
  }
#pragma unroll
  for (int mt = 0; mt < 2; mt++)
#pragma unroll
    for (int nt = 0; nt < 4; nt++)
#pragma unroll
      for (int r = 0; r < 4; r++) {
        int row = m0 + w * 32 + mt * 16 + q * 4 + r;
        int col = n0 + nt * 16 + r0;
        Cout[(size_t)row * N + col] = acc[mt][nt][r];
      }
}

// ---------------- flash attention: 32 queries/wave, work-uniform, XCD-L2-local ----------
// Decode bh = blk & 31 so XCD (= blk % 8 round-robin) serves only bh = c mod 8:
// 4 bh values -> <=4 (b,kvh) K/V sets (2 MB) + 4 Q heads (1 MB) fit the XCD's 4 MB L2.
// Block p handles 32-query chunks {p, 31-p, 32+p, 63-p}: work uniform by construction.
__global__ __launch_bounds__(256, 2) void attn_kernel(const bf16* __restrict__ Qb,
                                                      const bf16* __restrict__ Kf,
                                                      const bf16* __restrict__ Vf,
                                                      const int* __restrict__ wlp,
                                                      const int* __restrict__ wrp,
                                                      bf16* __restrict__ Yb) {
  const int wl = wlp[0];
  const int wrc = min(wrp[0], 0);  // j<=i+wr && j<=i  ==>  j <= i+min(wr,0)
  const int blk = blockIdx.x;
  const int bh = blk & 31, p = blk >> 5;  // XCD-local: blk%8 == bh%8
  const int b = bh >> 4, h = bh & 15, kvh = (bh & 15) >> 2;
  const int w = threadIdx.x >> 6, lane = threadIdx.x & 63;
  const int q = lane >> 4, r0 = lane & 15;
  // balanced chunk set: {p, 31-p, 32+p, 63-p}
  const int cm = (w == 0) ? p : (w == 1) ? 31 - p : (w == 2) ? 32 + p : 63 - p;
  const int q0 = cm * 32;
  const int qA = q0, qB = q0 + 16;

  const bf16* qbase = Qb + (((size_t)b * 16 + h) * 2048 + qA + r0) * 64;
  bf16x8 aqA0 = *(const bf16x8*)(qbase + q * 8);
  bf16x8 aqA1 = *(const bf16x8*)(qbase + 32 + q * 8);
  bf16x8 aqB0 = *(const bf16x8*)(qbase + 16 * 64 + q * 8);
  bf16x8 aqB1 = *(const bf16x8*)(qbase + 16 * 64 + 32 + q * 8);

  floatx4 OA[4], OB[4];
#pragma unroll
  for (int nt = 0; nt < 4; nt++) {
    OA[nt] = (floatx4){0.f, 0.f, 0.f, 0.f};
    OB[nt] = (floatx4){0.f, 0.f, 0.f, 0.f};
  }
  floatx4 LA = (floatx4){0.f, 0.f, 0.f, 0.f};
  floatx4 LB = LA;

  const bf16 onev = (bf16)1.0f;
  const bf16x8 ones = {onev, onev, onev, onev, onev, onev, onev, onev};

  const int jlo = max(0, q0 - wl) & ~31;
  const int jhi = q0 + 31 + wrc;
  const int count = ((jhi - jlo) >> 5) + 1;
  const int tile0 = jlo >> 5;

  const bf16* kfb = Kf + ((size_t)(b * 4 + kvh) * 64) * 2048 + lane * 8;
  const bf16* vfb = Vf + ((size_t)(b * 4 + kvh) * 64) * 2048 + lane * 8;

  bf16x8 kf[4], vf[4], nk[4], nv[4];
#pragma unroll
  for (int u = 0; u < 4; u++) {
    kf[u] = *(const bf16x8*)(kfb + (size_t)tile0 * 2048 + u * 512);
    vf[u] = *(const bf16x8*)(vfb + (size_t)tile0 * 2048 + u * 512);
  }

  for (int t = 0; t < count; t++) {
    const int j0 = jlo + (t << 5);
    // prefetch next tile (re-load current on last iter)
    const int tn = (t + 1 < count) ? tile0 + t + 1 : tile0 + t;
#pragma unroll
    for (int u = 0; u < 4; u++) {
      nk[u] = *(const bf16x8*)(kfb + (size_t)tn * 2048 + u * 512);
      nv[u] = *(const bf16x8*)(vfb + (size_t)tn * 2048 + u * 512);
    }

    // St = K·Q^T - SHIFT_C for both chunks (C-layout: row j-j0 = 4q+r (+16*sub), col = r0)
    floatx4 sA0 = (floatx4){-SHIFT_C, -SHIFT_C, -SHIFT_C, -SHIFT_C};
    floatx4 sA1 = sA0, sB0 = sA0, sB1 = sA0;
    sA0 = mfma16(kf[0], aqA0, sA0);
    sA0 = mfma16(kf[1], aqA1, sA0);
    sA1 = mfma16(kf[2], aqA0, sA1);
    sA1 = mfma16(kf[3], aqA1, sA1);
    sB0 = mfma16(kf[0], aqB0, sB0);
    sB0 = mfma16(kf[1], aqB1, sB0);
    sB1 = mfma16(kf[2], aqB0, sB1);
    sB1 = mfma16(kf[3], aqB1, sB1);

    bf16x8 paA, paB;
    // chunk A mask/exp
    if (j0 >= qA + 15 - wl && j0 + 31 <= qA + wrc) {
#pragma unroll
      for (int r = 0; r < 4; r++) {
        paA[r] = (bf16)exp2f(sA0[r]);
        paA[4 + r] = (bf16)exp2f(sA1[r]);
      }
    } else {
      const int i = qA + r0;
#pragma unroll
      for (int r = 0; r < 4; r++) {
        int ja = j0 + 4 * q + r, jb = ja + 16;
        bool va = (ja <= i + wrc) && (ja >= i - wl);
        bool vb = (jb <= i + wrc) && (jb >= i - wl);
        paA[r] = va ? (bf16)exp2f(sA0[r]) : (bf16)0.f;
        paA[4 + r] = vb ? (bf16)exp2f(sA1[r]) : (bf16)0.f;
      }
    }
    // chunk B mask/exp
    if (j0 >= qB + 15 - wl && j0 + 31 <= qB + wrc) {
#pragma unroll
      for (int r = 0; r < 4; r++) {
        paB[r] = (bf16)exp2f(sB0[r]);
        paB[4 + r] = (bf16)exp2f(sB1[r]);
      }
    } else {
      const int i = qB + r0;
#pragma unroll
      for (int r = 0; r < 4; r++) {
        int ja = j0 + 4 * q + r, jb = ja + 16;
        bool va = (ja <= i + wrc) && (ja >= i - wl);
        bool vb = (jb <= i + wrc) && (jb >= i - wl);
        paB[r] = va ? (bf16)exp2f(sB0[r]) : (bf16)0.f;
        paB[4 + r] = vb ? (bf16)exp2f(sB1[r]) : (bf16)0.f;
      }
    }

    LA = mfma16(paA, ones, LA);
    LB = mfma16(paB, ones, LB);
#pragma unroll
    for (int nt = 0; nt < 4; nt++) {
      OA[nt] = mfma16(paA, vf[nt], OA[nt]);
      OB[nt] = mfma16(paB, vf[nt], OB[nt]);
    }

#pragma unroll
    for (int u = 0; u < 4; u++) { kf[u] = nk[u]; vf[u] = nv[u]; }
  }

  // O/L C-layout: row i-qX = q*4+r, col d = nt*16+r0
  float invA[4], invB[4];
#pragma unroll
  for (int r = 0; r < 4; r++) {
    invA[r] = 1.f / LA[r];
    invB[r] = 1.f / LB[r];
  }
#pragma unroll
  for (int nt = 0; nt < 4; nt++)
#pragma unroll
    for (int r = 0; r < 4; r++) {
      int iA = qA + q * 4 + r;
      Yb[((size_t)b * 2048 + iA) * 1024 + h * 64 + nt * 16 + r0] = (bf16)(OA[nt][r] * invA[r]);
      int iB = qB + q * 4 + r;
      Yb[((size_t)b * 2048 + iB) * 1024 + h * 64 + nt * 16 + r0] = (bf16)(OB[nt][r] * invB[r]);
    }
}

// ---------------- launch ----------------
extern "C" void kernel_launch(void* const* d_in, const int* in_sizes, int n_in,
                              void* d_out, int out_size, void* d_ws, size_t ws_size,
                              hipStream_t stream) {
  const float* x     = (const float*)d_in[0];
  const float* ve    = (const float*)d_in[1];
  const float* cosb  = (const float*)d_in[2];
  const float* sinb  = (const float*)d_in[3];
  const float* Wq    = (const float*)d_in[4];
  const float* Wk    = (const float*)d_in[5];
  const float* Wv    = (const float*)d_in[6];
  const float* Wproj = (const float*)d_in[7];
  const float* Wgate = (const float*)d_in[8];
  const int* wl      = (const int*)d_in[9];
  const int* wr      = (const int*)d_in[10];

  char* ws = (char*)d_ws;
  bf16* Xb      = (bf16*)(ws);                 //  8,388,608 B: x bf16 [4096][1024]
  bf16* Wqkv_t  = (bf16*)(ws + 8388608);       //  3,145,728 B: [1536][1024]
  bf16* Wproj_t = (bf16*)(ws + 11534336);      //  2,097,152 B: [1024][1024]
  bf16* Qb      = (bf16*)(ws + 13631488);      //  8,388,608 B: [2][16][2048][64]
  bf16* Kf      = (bf16*)(ws + 22020096);      //  2,097,152 B: frag K [8][64 tiles][2048]
  bf16* Vf      = (bf16*)(ws + 24117248);      //  2,097,152 B: frag V
  bf16* Yb      = (bf16*)(ws + 26214400);      //  8,388,608 B: [4096][1024]
  float* gateb  = (float*)(ws + 34603008);     //     65,536 B: [2][4][2048]

  cast_gate_kernel<<<4096, 256, 0, stream>>>(x, Wgate, Xb, gateb);
  pack_w_kernel<<<dim3(80, 32), 256, 0, stream>>>(Wq, Wk, Wv, Wproj, Wqkv_t, Wproj_t);
  qkv_gemm_kernel<<<dim3(24, 32), 256, 0, stream>>>(Xb, Wqkv_t, ve, cosb, sinb, gateb, Qb, Kf, Vf);
  attn_kernel<<<512, 256, 0, stream>>>(Qb, Kf, Vf, wl, wr, Yb);
  proj_gemm_kernel<<<dim3(16, 32), 256, 0, stream>>>(Yb, Wproj_t, (float*)d_out);
}

// Round 12
// 168.336 us; speedup vs baseline: 1.1923x; 1.0216x over previous
//
#include <hip/hip_runtime.h>

typedef __bf16 bf16;
typedef __bf16 bf16x4 __attribute__((ext_vector_type(4)));
typedef __bf16 bf16x8 __attribute__((ext_vector_type(8)));
typedef float floatx4 __attribute__((ext_vector_type(4)));

#define EPS 1.1920929e-07f
// q scale = D^-0.5 * log2(e) folded together (D=64 -> 0.125)
#define QSCALE (0.125f * 1.44269504088896f)
// fixed softmax shift: |q_eff . k| <= ||q_eff||*||k|| = (8*QSCALE)*8 = 11.5416
#define SHIFT_C 11.5416f

__device__ __forceinline__ floatx4 mfma16(bf16x8 a, bf16x8 b, floatx4 c) {
  return __builtin_amdgcn_mfma_f32_16x16x32_bf16(a, b, c, 0, 0, 0);
}

// async 16B global->LDS: HW writes ldsbase + lane*16; gptr is per-lane
__device__ __forceinline__ void gload16(const void* g, void* l) {
  __builtin_amdgcn_global_load_lds((const __attribute__((address_space(1))) unsigned int*)g,
                                   (__attribute__((address_space(3))) unsigned int*)l, 16, 0, 0);
}

// ---------------- fused cast + gate: one block per token ----------------
__global__ void cast_gate_kernel(const float* __restrict__ x, const float* __restrict__ wgate,
                                 bf16* __restrict__ xb, float* __restrict__ gate) {
  int t = blockIdx.x, tid = threadIdx.x;
  const float* xr = x + (size_t)t * 1024;
  float4 v = *(const float4*)(xr + tid * 4);
  bf16x4 o = {(bf16)v.x, (bf16)v.y, (bf16)v.z, (bf16)v.w};
  *(bf16x4*)(xb + (size_t)t * 1024 + tid * 4) = o;
  if (tid < 64) {
    int c = (tid & 31) * 4;  // gate columns come from lanes 0..31 only
#pragma unroll
    for (int kv = 0; kv < 4; kv++) {
      float g = v.x * wgate[(c + 0) * 4 + kv] + v.y * wgate[(c + 1) * 4 + kv] +
                v.z * wgate[(c + 2) * 4 + kv] + v.w * wgate[(c + 3) * 4 + kv];
      g += __shfl_xor(g, 1, 64);
      g += __shfl_xor(g, 2, 64);
      g += __shfl_xor(g, 4, 64);
      g += __shfl_xor(g, 8, 64);
      g += __shfl_xor(g, 16, 64);
      if (tid == 0) {
        int b = t >> 11, s = t & 2047;
        gate[((size_t)b * 4 + kv) * 2048 + s] = 2.f / (1.f + __expf(-g));
      }
    }
  }
}

// ---------------- combined weight pack: qkv (x<48) + wproj (x>=48) ----------------
__global__ void pack_w_kernel(const float* __restrict__ Wq, const float* __restrict__ Wk,
                              const float* __restrict__ Wv, const float* __restrict__ Wproj,
                              bf16* __restrict__ out_qkv, bf16* __restrict__ out_proj) {
  __shared__ float tile[32][33];
  int k0 = blockIdx.y * 32;
  int tx = threadIdx.x & 31, ty = threadIdx.x >> 5;
  if (blockIdx.x < 48) {
    int n0 = blockIdx.x * 32;
#pragma unroll
    for (int i = 0; i < 4; i++) {
      int k = k0 + ty + i * 8, n = n0 + tx;
      float v;
      if (n < 1024)      v = Wq[(size_t)k * 1024 + n];
      else if (n < 1280) v = Wk[(size_t)k * 256 + (n - 1024)];
      else               v = Wv[(size_t)k * 256 + (n - 1280)];
      tile[ty + i * 8][tx] = v;
    }
    __syncthreads();
#pragma unroll
    for (int i = 0; i < 4; i++) {
      int n = n0 + ty + i * 8, k = k0 + tx;
      out_qkv[(size_t)n * 1024 + k] = (bf16)tile[tx][ty + i * 8];
    }
  } else {
    int n0 = (blockIdx.x - 48) * 32;
#pragma unroll
    for (int i = 0; i < 4; i++)
      tile[ty + i * 8][tx] = Wproj[(size_t)(k0 + ty + i * 8) * 1024 + n0 + tx];
    __syncthreads();
#pragma unroll
    for (int i = 0; i < 4; i++)
      out_proj[(size_t)(n0 + ty + i * 8) * 1024 + k0 + tx] = (bf16)tile[tx][ty + i * 8];
  }
}

// ---------------- fused QKV GEMM: 128m x 64n tiles, BK=64, + RoPE/RMS/gate epilogue ----
// blockIdx.x = n-tile (64 cols = one head): 0-15 Q heads, 16-19 K kv, 20-23 V kv.
// 4 waves, each 32m x 64n. LDS: two 32-col sub-tiles per operand (proven bank-safe layout).
__global__ __launch_bounds__(256) void qkv_gemm_kernel(const bf16* __restrict__ A,
                                                       const bf16* __restrict__ Bt,
                                                       const float* __restrict__ ve,
                                                       const float* __restrict__ cosb,
                                                       const float* __restrict__ sinb,
                                                       const float* __restrict__ gate,
                                                       bf16* __restrict__ Qb,
                                                       bf16* __restrict__ Kf,
                                                       bf16* __restrict__ Vf) {
  __shared__ __align__(16) char smem[24576];  // As 16K (2 halves x 128 x 32) + Bs 8K; epilogue Ep 128x72 bf16
  bf16* As = (bf16*)smem;
  bf16* Bs = (bf16*)(smem + 16384);
  bf16* Ep = (bf16*)smem;
  const int K = 1024;
  const int tid = threadIdx.x;
  const int tile = blockIdx.x;
  const int m0 = blockIdx.y * 128, n0 = tile * 64;
  const int w = tid >> 6, lane = tid & 63;
  const int q = lane >> 4, r0 = lane & 15;
  const int lrow = lane >> 2, lcol = (lane & 3) * 8;
  const int b = m0 >> 11, s0 = m0 & 2047;

  floatx4 acc[2][4];
#pragma unroll
  for (int i = 0; i < 2; i++)
#pragma unroll
    for (int j = 0; j < 4; j++) acc[i][j] = (floatx4){0.f, 0.f, 0.f, 0.f};

  for (int k0 = 0; k0 < K; k0 += 64) {
    __syncthreads();
    // A: 16 gloads (half s, row-block rb): wave w issues g = w*4..w*4+3
#pragma unroll
    for (int i = 0; i < 4; i++) {
      int g = w * 4 + i, s = g >> 3, rb = g & 7;
      gload16(A + (size_t)(m0 + rb * 16 + lrow) * K + k0 + s * 32 + lcol, &As[s * 4096 + rb * 512]);
    }
    // B: 8 gloads: wave w issues g = w*2, w*2+1
#pragma unroll
    for (int i = 0; i < 2; i++) {
      int g = w * 2 + i, s = g >> 2, rb = g & 3;
      gload16(Bt + (size_t)(n0 + rb * 16 + lrow) * K + k0 + s * 32 + lcol, &Bs[s * 2048 + rb * 512]);
    }
    __syncthreads();
#pragma unroll
    for (int s = 0; s < 2; s++) {
      bf16x8 af[2], bfr[4];
#pragma unroll
      for (int mt = 0; mt < 2; mt++) af[mt] = *(const bf16x8*)&As[s * 4096 + (w * 32 + mt * 16 + r0) * 32 + q * 8];
#pragma unroll
      for (int nt = 0; nt < 4; nt++) bfr[nt] = *(const bf16x8*)&Bs[s * 2048 + (nt * 16 + r0) * 32 + q * 8];
#pragma unroll
      for (int mt = 0; mt < 2; mt++)
#pragma unroll
        for (int nt = 0; nt < 4; nt++)
          acc[mt][nt] = mfma16(af[mt], bfr[nt], acc[mt][nt]);
    }
  }
  __syncthreads();  // all LDS reads done; Ep reuses the space

  // lane owns rows w*32 + mt*16 + q*4 + r (token - m0), d = nt*16 + r0
  if (tile < 16) {
    // ---- Q: rope -> rms -> *QSCALE -> Ep -> coalesced Qb copy ----
    const int h = tile;
#pragma unroll
    for (int mt = 0; mt < 2; mt++) {
      float rvv[4][4];
#pragma unroll
      for (int ntp = 0; ntp < 2; ntp++) {
        int d31 = ntp * 16 + r0;
#pragma unroll
        for (int r = 0; r < 4; r++) {
          int s = s0 + w * 32 + mt * 16 + q * 4 + r;
          float c = cosb[s * 32 + d31], sn = sinb[s * 32 + d31];
          float v1 = acc[mt][ntp][r], v2 = acc[mt][ntp + 2][r];
          rvv[ntp][r] = v1 * c + v2 * sn;
          rvv[ntp + 2][r] = v2 * c - v1 * sn;
        }
      }
#pragma unroll
      for (int r = 0; r < 4; r++) {
        float ss = 0.f;
#pragma unroll
        for (int nt = 0; nt < 4; nt++) ss += rvv[nt][r] * rvv[nt][r];
        ss += __shfl_xor(ss, 1, 64);
        ss += __shfl_xor(ss, 2, 64);
        ss += __shfl_xor(ss, 4, 64);
        ss += __shfl_xor(ss, 8, 64);
        float sc = rsqrtf(ss * (1.f / 64.f) + EPS) * QSCALE;
        int row = w * 32 + mt * 16 + q * 4 + r;
#pragma unroll
        for (int nt = 0; nt < 4; nt++)
          Ep[row * 72 + nt * 16 + r0] = (bf16)(rvv[nt][r] * sc);
      }
    }
    __syncthreads();
#pragma unroll
    for (int p = 0; p < 4; p++) {
      int g = p * 256 + tid;
      int row = g >> 3, chunk = g & 7;
      *(uint4*)&Qb[(((size_t)b * 16 + h) * 2048 + s0 + row) * 64 + chunk * 8] =
          *(const uint4*)&Ep[row * 72 + chunk * 8];
    }
  } else if (tile < 20) {
    // ---- K: rope -> rms -> Ep -> Kf fragment layout ----
    const int kv = tile - 16;
#pragma unroll
    for (int mt = 0; mt < 2; mt++) {
      float rvv[4][4];
#pragma unroll
      for (int ntp = 0; ntp < 2; ntp++) {
        int d31 = ntp * 16 + r0;
#pragma unroll
        for (int r = 0; r < 4; r++) {
          int s = s0 + w * 32 + mt * 16 + q * 4 + r;
          float c = cosb[s * 32 + d31], sn = sinb[s * 32 + d31];
          float v1 = acc[mt][ntp][r], v2 = acc[mt][ntp + 2][r];
          rvv[ntp][r] = v1 * c + v2 * sn;
          rvv[ntp + 2][r] = v2 * c - v1 * sn;
        }
      }
#pragma unroll
      for (int r = 0; r < 4; r++) {
        float ss = 0.f;
#pragma unroll
        for (int nt = 0; nt < 4; nt++) ss += rvv[nt][r] * rvv[nt][r];
        ss += __shfl_xor(ss, 1, 64);
        ss += __shfl_xor(ss, 2, 64);
        ss += __shfl_xor(ss, 4, 64);
        ss += __shfl_xor(ss, 8, 64);
        float sc = rsqrtf(ss * (1.f / 64.f) + EPS);
        int row = w * 32 + mt * 16 + q * 4 + r;
#pragma unroll
        for (int nt = 0; nt < 4; nt++)
          Ep[row * 72 + nt * 16 + r0] = (bf16)(rvv[nt][r] * sc);
      }
    }
    __syncthreads();
    // each wave extracts frags for its own 32-key sub-tile
    {
      int tk = (s0 >> 5) + w;
      size_t tb = ((size_t)(b * 4 + kv) * 64 + tk) * 2048;
#pragma unroll
      for (int u = 0; u < 4; u++) {
        int joff = (u >= 2) ? 16 : 0, doff = (u & 1) * 32;
        bf16x8 f = *(const bf16x8*)&Ep[(w * 32 + joff + r0) * 72 + doff + q * 8];
        *(bf16x8*)&Kf[tb + u * 512 + lane * 8] = f;
      }
    }
  } else {
    // ---- V: + gate*ve -> Ep -> Vf fragment layout ----
    const int kv = tile - 20;
    const float* gbase = gate + ((size_t)b * 4 + kv) * 2048;
#pragma unroll
    for (int mt = 0; mt < 2; mt++) {
#pragma unroll
      for (int r = 0; r < 4; r++) {
        int row = w * 32 + mt * 16 + q * 4 + r;
        float gg = gbase[s0 + row];
#pragma unroll
        for (int nt = 0; nt < 4; nt++) {
          int d = nt * 16 + r0;
          float vv = acc[mt][nt][r] + gg * ve[(size_t)(m0 + row) * 256 + kv * 64 + d];
          Ep[row * 72 + d] = (bf16)vv;
        }
      }
    }
    __syncthreads();
    {
      int tk = (s0 >> 5) + w;
      size_t tb = ((size_t)(b * 4 + kv) * 64 + tk) * 2048;
#pragma unroll
      for (int nt = 0; nt < 4; nt++) {
        bf16 tmp[8];
#pragma unroll
        for (int e = 0; e < 8; e++) {
          int jl = w * 32 + (e >> 2) * 16 + 4 * q + (e & 3);
          tmp[e] = Ep[jl * 72 + nt * 16 + r0];
        }
        *(uint4*)&Vf[tb + nt * 512 + lane * 8] = *(uint4*)tmp;
      }
    }
  }
}

// ---------------- proj GEMM: 128m x 64n, BK=64, fp32 out ----------------
__global__ __launch_bounds__(256) void proj_gemm_kernel(const bf16* __restrict__ A,
                                                        const bf16* __restrict__ Bt,
                                                        float* __restrict__ Cout) {
  __shared__ __align__(16) bf16 As[2 * 128 * 32];
  __shared__ __align__(16) bf16 Bs[2 * 64 * 32];
  const int K = 1024, N = 1024;
  const int tid = threadIdx.x;
  const int m0 = blockIdx.y * 128, n0 = blockIdx.x * 64;
  const int w = tid >> 6, lane = tid & 63;
  const int q = lane >> 4, r0 = lane & 15;
  const int lrow = lane >> 2, lcol = (lane & 3) * 8;

  floatx4 acc[2][4];
#pragma unroll
  for (int i = 0; i < 2; i++)
#pragma unroll
    for (int j = 0; j < 4; j++) acc[i][j] = (floatx4){0.f, 0.f, 0.f, 0.f};

  for (int k0 = 0; k0 < K; k0 += 64) {
    __syncthreads();
#pragma unroll
    for (int i = 0; i < 4; i++) {
      int g = w * 4 + i, s = g >> 3, rb = g & 7;
      gload16(A + (size_t)(m0 + rb * 16 + lrow) * K + k0 + s * 32 + lcol, &As[s * 4096 + rb * 512]);
    }
#pragma unroll
    for (int i = 0; i < 2; i++) {
      int g = w * 2 + i, s = g >> 2, rb = g & 3;
      gload16(Bt + (size_t)(n0 + rb * 16 + lrow) * K + k0 + s * 32 + lcol, &Bs[s * 2048 + rb * 512]);
    }
    __syncthreads();
#pragma unroll
    for (int s = 0; s < 2; s++) {
      bf16x8 af[2], bfr[4];
#pragma unroll
      for (int mt = 0; mt < 2; mt++) af[mt] = *(const bf16x8*)&As[s * 4096 + (w * 32 + mt * 16 + r0) * 32 + q * 8];
#pragma unroll
      for (int nt = 0; nt < 4; nt++) bfr[nt] = *(const bf16x8*)&Bs[s * 2048 + (nt * 16 + r0) * 32 + q * 8];
#pragma unroll
      for (int mt = 0; mt < 2; mt++)
#pragma unroll
        for (int nt = 0; nt < 4; nt++)
          acc[mt][nt] = mfma16(af[mt], bfr[nt], acc[mt][nt]);
    }
  }
#pragma unroll
  for (int mt = 0; mt < 2; mt++)
#pragma unroll
    for (int nt = 0; nt < 4; nt++)
#pragma unroll
      for (int r = 0; r < 4; r++) {
        int row = m0 + w * 32 + mt * 16 + q * 4 + r;
        int col = n0 + nt * 16 + r0;
        Cout[(size_t)row * N + col] = acc[mt][nt][r];
      }
}

// ---------------- flash attention: GQA-shared K/V streams, 32 q/wave, work-uniform ----
// Block = (b, kvh, cpair): 8 waves. Wave w: head h = kvh*4 + (w&3), chunk = (w<4) ?
// cpair : 63-cpair. The 4 waves sharing a chunk read IDENTICAL K/V fragment addresses
// in near-lockstep -> 1 L2 fill + 3 L1 hits (same CU): aggregate cache traffic /4.
// Work/block = window(c)+window(63-c) = constant -> uniform by construction.
__global__ __launch_bounds__(512) void attn_kernel(const bf16* __restrict__ Qb,
                                                   const bf16* __restrict__ Kf,
                                                   const bf16* __restrict__ Vf,
                                                   const int* __restrict__ wlp,
                                                   const int* __restrict__ wrp,
                                                   bf16* __restrict__ Yb) {
  const int wl = wlp[0];
  const int wrc = min(wrp[0], 0);  // j<=i+wr && j<=i  ==>  j <= i+min(wr,0)
  const int blk = blockIdx.x;
  const int cpair = blk & 31, bkv = blk >> 5;  // bkv 0..7
  const int b = bkv >> 2, kvh = bkv & 3;
  const int w = threadIdx.x >> 6, lane = threadIdx.x & 63;
  const int q = lane >> 4, r0 = lane & 15;
  const int h = kvh * 4 + (w & 3);
  const int cm = (w < 4) ? cpair : 63 - cpair;
  const int q0 = cm * 32;
  const int qA = q0, qB = q0 + 16;

  const bf16* qbase = Qb + (((size_t)b * 16 + h) * 2048 + qA + r0) * 64;
  bf16x8 aqA0 = *(const bf16x8*)(qbase + q * 8);
  bf16x8 aqA1 = *(const bf16x8*)(qbase + 32 + q * 8);
  bf16x8 aqB0 = *(const bf16x8*)(qbase + 16 * 64 + q * 8);
  bf16x8 aqB1 = *(const bf16x8*)(qbase + 16 * 64 + 32 + q * 8);

  floatx4 OA[4], OB[4];
#pragma unroll
  for (int nt = 0; nt < 4; nt++) {
    OA[nt] = (floatx4){0.f, 0.f, 0.f, 0.f};
    OB[nt] = (floatx4){0.f, 0.f, 0.f, 0.f};
  }
  floatx4 LA = (floatx4){0.f, 0.f, 0.f, 0.f};
  floatx4 LB = LA;

  const bf16 onev = (bf16)1.0f;
  const bf16x8 ones = {onev, onev, onev, onev, onev, onev, onev, onev};

  const int jlo = max(0, q0 - wl) & ~31;
  const int jhi = q0 + 31 + wrc;
  const int count = ((jhi - jlo) >> 5) + 1;
  const int tile0 = jlo >> 5;

  const bf16* kfb = Kf + ((size_t)(b * 4 + kvh) * 64) * 2048 + lane * 8;
  const bf16* vfb = Vf + ((size_t)(b * 4 + kvh) * 64) * 2048 + lane * 8;

  bf16x8 kf[4], vf[4], nk[4], nv[4];
#pragma unroll
  for (int u = 0; u < 4; u++) {
    kf[u] = *(const bf16x8*)(kfb + (size_t)tile0 * 2048 + u * 512);
    vf[u] = *(const bf16x8*)(vfb + (size_t)tile0 * 2048 + u * 512);
  }

  for (int t = 0; t < count; t++) {
    const int j0 = jlo + (t << 5);
    // prefetch next tile (re-load current on last iter)
    const int tn = (t + 1 < count) ? tile0 + t + 1 : tile0 + t;
#pragma unroll
    for (int u = 0; u < 4; u++) {
      nk[u] = *(const bf16x8*)(kfb + (size_t)tn * 2048 + u * 512);
      nv[u] = *(const bf16x8*)(vfb + (size_t)tn * 2048 + u * 512);
    }

    // St = K·Q^T - SHIFT_C for both chunks (C-layout: row j-j0 = 4q+r (+16*sub), col = r0)
    floatx4 sA0 = (floatx4){-SHIFT_C, -SHIFT_C, -SHIFT_C, -SHIFT_C};
    floatx4 sA1 = sA0, sB0 = sA0, sB1 = sA0;
    sA0 = mfma16(kf[0], aqA0, sA0);
    sA0 = mfma16(kf[1], aqA1, sA0);
    sA1 = mfma16(kf[2], aqA0, sA1);
    sA1 = mfma16(kf[3], aqA1, sA1);
    sB0 = mfma16(kf[0], aqB0, sB0);
    sB0 = mfma16(kf[1], aqB1, sB0);
    sB1 = mfma16(kf[2], aqB0, sB1);
    sB1 = mfma16(kf[3], aqB1, sB1);

    bf16x8 paA, paB;
    // chunk A mask/exp
    if (j0 >= qA + 15 - wl && j0 + 31 <= qA + wrc) {
#pragma unroll
      for (int r = 0; r < 4; r++) {
        paA[r] = (bf16)exp2f(sA0[r]);
        paA[4 + r] = (bf16)exp2f(sA1[r]);
      }
    } else {
      const int i = qA + r0;
#pragma unroll
      for (int r = 0; r < 4; r++) {
        int ja = j0 + 4 * q + r, jb = ja + 16;
        bool va = (ja <= i + wrc) && (ja >= i - wl);
        bool vb = (jb <= i + wrc) && (jb >= i - wl);
        paA[r] = va ? (bf16)exp2f(sA0[r]) : (bf16)0.f;
        paA[4 + r] = vb ? (bf16)exp2f(sA1[r]) : (bf16)0.f;
      }
    }
    // chunk B mask/exp
    if (j0 >= qB + 15 - wl && j0 + 31 <= qB + wrc) {
#pragma unroll
      for (int r = 0; r < 4; r++) {
        paB[r] = (bf16)exp2f(sB0[r]);
        paB[4 + r] = (bf16)exp2f(sB1[r]);
      }
    } else {
      const int i = qB + r0;
#pragma unroll
      for (int r = 0; r < 4; r++) {
        int ja = j0 + 4 * q + r, jb = ja + 16;
        bool va = (ja <= i + wrc) && (ja >= i - wl);
        bool vb = (jb <= i + wrc) && (jb >= i - wl);
        paB[r] = va ? (bf16)exp2f(sB0[r]) : (bf16)0.f;
        paB[4 + r] = vb ? (bf16)exp2f(sB1[r]) : (bf16)0.f;
      }
    }

    LA = mfma16(paA, ones, LA);
    LB = mfma16(paB, ones, LB);
#pragma unroll
    for (int nt = 0; nt < 4; nt++) {
      OA[nt] = mfma16(paA, vf[nt], OA[nt]);
      OB[nt] = mfma16(paB, vf[nt], OB[nt]);
    }

#pragma unroll
    for (int u = 0; u < 4; u++) { kf[u] = nk[u]; vf[u] = nv[u]; }
  }

  // O/L C-layout: row i-qX = q*4+r, col d = nt*16+r0
  float invA[4], invB[4];
#pragma unroll
  for (int r = 0; r < 4; r++) {
    invA[r] = 1.f / LA[r];
    invB[r] = 1.f / LB[r];
  }
#pragma unroll
  for (int nt = 0; nt < 4; nt++)
#pragma unroll
    for (int r = 0; r < 4; r++) {
      int iA = qA + q * 4 + r;
      Yb[((size_t)b * 2048 + iA) * 1024 + h * 64 + nt * 16 + r0] = (bf16)(OA[nt][r] * invA[r]);
      int iB = qB + q * 4 + r;
      Yb[((size_t)b * 2048 + iB) * 1024 + h * 64 + nt * 16 + r0] = (bf16)(OB[nt][r] * invB[r]);
    }
}

// ---------------- launch ----------------
extern "C" void kernel_launch(void* const* d_in, const int* in_sizes, int n_in,
                              void* d_out, int out_size, void* d_ws, size_t ws_size,
                              hipStream_t stream) {
  const float* x     = (const float*)d_in[0];
  const float* ve    = (const float*)d_in[1];
  const float* cosb  = (const float*)d_in[2];
  const float* sinb  = (const float*)d_in[3];
  const float* Wq    = (const float*)d_in[4];
  const float* Wk    = (const float*)d_in[5];
  const float* Wv    = (const float*)d_in[6];
  const float* Wproj = (const float*)d_in[7];
  const float* Wgate = (const float*)d_in[8];
  const int* wl      = (const int*)d_in[9];
  const int* wr      = (const int*)d_in[10];

  char* ws = (char*)d_ws;
  bf16* Xb      = (bf16*)(ws);                 //  8,388,608 B: x bf16 [4096][1024]
  bf16* Wqkv_t  = (bf16*)(ws + 8388608);       //  3,145,728 B: [1536][1024]
  bf16* Wproj_t = (bf16*)(ws + 11534336);      //  2,097,152 B: [1024][1024]
  bf16* Qb      = (bf16*)(ws + 13631488);      //  8,388,608 B: [2][16][2048][64]
  bf16* Kf      = (bf16*)(ws + 22020096);      //  2,097,152 B: frag K [8][64 tiles][2048]
  bf16* Vf      = (bf16*)(ws + 24117248);      //  2,097,152 B: frag V
  bf16* Yb      = (bf16*)(ws + 26214400);      //  8,388,608 B: [4096][1024]
  float* gateb  = (float*)(ws + 34603008);     //     65,536 B: [2][4][2048]

  cast_gate_kernel<<<4096, 256, 0, stream>>>(x, Wgate, Xb, gateb);
  pack_w_kernel<<<dim3(80, 32), 256, 0, stream>>>(Wq, Wk, Wv, Wproj, Wqkv_t, Wproj_t);
  qkv_gemm_kernel<<<dim3(24, 32), 256, 0, stream>>>(Xb, Wqkv_t, ve, cosb, sinb, gateb, Qb, Kf, Vf);
  attn_kernel<<<256, 512, 0, stream>>>(Qb, Kf, Vf, wl, wr, Yb);
  proj_gemm_kernel<<<dim3(16, 32), 256, 0, stream>>>(Yb, Wproj_t, (float*)d_out);
}